// Round 4
// baseline (235.133 us; speedup 1.0000x reference)
//
#include <hip/hip_runtime.h>
#include <math.h>

// Problem constants
#define Bc 2
#define Tc 2048
#define Dc 1024
#define Hc 16
#define HDc 64
// M = B*T = 4096, QKV N = 3072, K = 1024

typedef __attribute__((ext_vector_type(8))) short bf16x8;
typedef __attribute__((ext_vector_type(4))) float f32x4;
typedef __attribute__((ext_vector_type(16))) float f32x16;

__device__ __forceinline__ unsigned short f2bf(float f) {
    union { float f; unsigned int u; } v; v.f = f;
    unsigned int r = (v.u + 0x7FFFu + ((v.u >> 16) & 1u)) >> 16;   // RNE
    return (unsigned short)r;
}
// pack two fp32 -> bf16x2 dword (round-nearest, ties up): 3 VALU
__device__ __forceinline__ unsigned pack2bf(float a, float b) {
    unsigned au = __float_as_uint(a) + 0x8000u;
    unsigned bu = __float_as_uint(b) + 0x8000u;
    return __builtin_amdgcn_perm(bu, au, 0x07060302u);
}

// async global->LDS, 16 B per lane. LDS dest is WAVE-UNIFORM base + lane*16.
__device__ __forceinline__ void gload_lds16(const unsigned short* g,
                                            unsigned short* l) {
    __builtin_amdgcn_global_load_lds(
        (const __attribute__((address_space(1))) unsigned int*)g,
        (__attribute__((address_space(3))) unsigned int*)l,
        16, 0, 0);
}

// exp scale: 1/sqrt(64) * log2(e)  (fixed-max softmax: p = exp2(s*CEXP))
#define CEXP 0.1803368801111204f

// ---------------------------------------------------------------------------
// fp32 -> bf16 conversion for x, W_qkv, W_out + RoPE cos/sin table fill.
// ---------------------------------------------------------------------------
__global__ __launch_bounds__(256) void convert_bf16(
    const float* __restrict__ x, const float* __restrict__ wqkv,
    const float* __restrict__ wout,
    unsigned short* __restrict__ xb, unsigned short* __restrict__ wqkvb,
    unsigned short* __restrict__ woutb, float2* __restrict__ ropeTab)
{
    const int gid = blockIdx.x * 256 + threadIdx.x;
    // RoPE table: 2048 x 32 entries (cos, sin), angle = t * 10000^(-i/32)
    if (gid < Tc * 32) {
        const int t = gid >> 5, i = gid & 31;
        const float freq = exp2f((float)i * -0.4152410118609203f);
        const float ang = (float)t * freq;
        ropeTab[gid] = make_float2(cosf(ang), sinf(ang));
    }
    const int i = gid * 4;                        // 8,388,608 floats total
    const float* src; unsigned short* dst; int off;
    if (i < 4194304)      { src = x;    dst = xb;    off = i; }
    else if (i < 7340032) { src = wqkv; dst = wqkvb; off = i - 4194304; }
    else                  { src = wout; dst = woutb; off = i - 7340032; }
    float4 v = *(const float4*)&src[off];
    ushort4 o;
    o.x = f2bf(v.x); o.y = f2bf(v.y); o.z = f2bf(v.z); o.w = f2bf(v.w);
    *(ushort4*)&dst[off] = o;
}

// ---------------------------------------------------------------------------
// bf16 MFMA GEMM:  C[M,N] = A[M,K] @ W[N,K]^T + bias[N]
// BM=BN=128, BK=64, 256 thr = 4 waves (2x2), 64x64 per wave.
// Staging: async global_load_lds width=16 (linear LDS dest), with the global
// source oct PRE-SWIZZLED so LDS[r][o] = G[r][o ^ (r&7)] -> fragment reads
// (unchanged XOR addressing) stay 2-way-conflict-free (free per m136).
// MODE 0: fp32 C row-major + bias
// MODE 1: bf16 scatter with FUSED RoPE on Q,K -> [b,h,t,d]; V -> [b,h,d,t].
// ---------------------------------------------------------------------------
template <int MODE>
__global__ __launch_bounds__(256) void gemm_mfma(
    const unsigned short* __restrict__ A, const unsigned short* __restrict__ W,
    const float* __restrict__ bias, float* __restrict__ C,
    unsigned short* __restrict__ Qp, unsigned short* __restrict__ Kp,
    unsigned short* __restrict__ Vtp, const float2* __restrict__ ropeTab,
    int M, int N, int K)
{
    __shared__ unsigned short Apk[128 * 8 * 8];
    __shared__ unsigned short Bpk[128 * 8 * 8];

    const int tid = threadIdx.x;
    const int lane = tid & 63;
    const int wave = tid >> 6;
    const int quad = lane >> 4;
    const int c = lane & 15;
    const int wm = wave >> 1;
    const int wn = wave & 1;
    const int m0 = blockIdx.y * 128;
    const int n0 = blockIdx.x * 128;

    f32x4 acc[4][4];
#pragma unroll
    for (int mt = 0; mt < 4; mt++)
#pragma unroll
        for (int nt = 0; nt < 4; nt++) acc[mt][nt] = (f32x4){0.f, 0.f, 0.f, 0.f};

    // staging: wave-load of 1 KB covers 8 rows x 8 octs. lane -> (row, oct):
    // row_in_chunk = lane>>3, lds oct = lane&7 (fixed by HW linear layout).
    // source oct = (lane&7) ^ (r&7); since r&7 == lane>>3 for all chunks,
    // it's the lane-only constant below.
    const int lrow = lane >> 3;
    const int srcoct = (lane & 7) ^ lrow;

    for (int k0 = 0; k0 < K; k0 += 64) {
        __syncthreads();                       // prior tile's ds_reads done
#pragma unroll
        for (int i = 0; i < 4; i++) {
            const int r = wave * 32 + i * 8 + lrow;
            gload_lds16(&A[(size_t)(m0 + r) * K + k0 + srcoct * 8],
                        &Apk[(wave * 32 + i * 8) * 64]);
            gload_lds16(&W[(size_t)(n0 + r) * K + k0 + srcoct * 8],
                        &Bpk[(wave * 32 + i * 8) * 64]);
        }
        __syncthreads();                       // drains vmcnt(0): tile ready
#pragma unroll
        for (int ko = 0; ko < 2; ko++) {
            bf16x8 af[4], bf[4];
#pragma unroll
            for (int mt = 0; mt < 4; mt++) {
                const int m = wm * 64 + mt * 16 + c;
                af[mt] = *(const bf16x8*)&Apk[(m * 8 + ((ko * 4 + quad) ^ (m & 7))) * 8];
            }
#pragma unroll
            for (int nt = 0; nt < 4; nt++) {
                const int n = wn * 64 + nt * 16 + c;
                bf[nt] = *(const bf16x8*)&Bpk[(n * 8 + ((ko * 4 + quad) ^ (n & 7))) * 8];
            }
#pragma unroll
            for (int mt = 0; mt < 4; mt++)
#pragma unroll
                for (int nt = 0; nt < 4; nt++)
                    acc[mt][nt] = __builtin_amdgcn_mfma_f32_16x16x32_bf16(
                        af[mt], bf[nt], acc[mt][nt], 0, 0, 0);
        }
    }

    if (MODE == 0) {
#pragma unroll
        for (int mt = 0; mt < 4; mt++) {
            const int m = m0 + wm * 64 + mt * 16 + quad * 4;
#pragma unroll
            for (int nt = 0; nt < 4; nt++) {
                const int n = n0 + wn * 64 + nt * 16 + c;
                const float bv = bias[n];
#pragma unroll
                for (int reg = 0; reg < 4; reg++)
                    C[(size_t)(m + reg) * N + n] = acc[mt][nt][reg] + bv;
            }
        }
    } else {
        const int n_wave = n0 + wn * 64;          // 64-aligned -> one head/wave
        const int which = n_wave >> 10;           // 0=q,1=k,2=v (block-uniform)
        const int h = (n_wave >> 6) & 15;
        const int b = m0 >> 11;
        const int t_base = (m0 & 2047) + wm * 64;

        __syncthreads();   // all MFMA LDS reads done; reuse Apk/Bpk as staging
        // per-wave 8-KB staging region (wave-private; DS ops in-order per wave)
        unsigned short* stg = ((wave < 2) ? Apk : Bpk) + (wave & 1) * 4096;

        if (which < 2) {
            // ---- Q/K with fused RoPE: rotate -> LDS tile -> coalesced store
            unsigned short* dst = (which == 0) ? Qp : Kp;
#pragma unroll
            for (int mt = 0; mt < 4; mt++) {
#pragma unroll
                for (int nt = 0; nt < 2; nt++) {
                    const int i1 = nt * 16 + c;            // rotary index 0..31
                    const float bv1 = bias[n_wave + i1];
                    const float bv2 = bias[n_wave + 32 + i1];
#pragma unroll
                    for (int reg = 0; reg < 4; reg++) {
                        const int row = mt * 16 + quad * 4 + reg;
                        const float2 cs = ropeTab[(t_base + row) * 32 + i1];
                        const float x1 = acc[mt][nt][reg] + bv1;
                        const float x2 = acc[mt][nt + 2][reg] + bv2;
                        const int col2 = 32 + i1;
                        stg[(row * 8 + ((i1 >> 3) ^ (row & 7))) * 8 + (i1 & 7)] =
                            f2bf(x1 * cs.x - x2 * cs.y);
                        stg[(row * 8 + ((col2 >> 3) ^ (row & 7))) * 8 + (col2 & 7)] =
                            f2bf(x1 * cs.y + x2 * cs.x);
                    }
                }
            }
            // tile [t_base..t_base+63][0..63] is 8 KB CONTIGUOUS in Q/K
            const size_t obase = ((size_t)(b * Hc + h) * Tc + t_base) * HDc;
            const int oct = lane & 7;
#pragma unroll
            for (int k = 0; k < 8; k++) {
                const int f = lane * 8 + k * 512;       // flat ushort offset
                const int row = f >> 6;
                bf16x8 vv = *(const bf16x8*)&stg[(row * 8 + (oct ^ (row & 7))) * 8];
                *(bf16x8*)&dst[obase + f] = vv;         // 64 lanes x 16 B = 1 KB
            }
        } else {
            // ---- V: stage transposed tile [d][t], store full 128-B d-rows
#pragma unroll
            for (int mt = 0; mt < 4; mt++) {
#pragma unroll
                for (int nt = 0; nt < 4; nt++) {
                    const int d = nt * 16 + c;
                    const float bv = bias[n_wave + d];
#pragma unroll
                    for (int reg = 0; reg < 4; reg++) {
                        const int r = mt * 16 + quad * 4 + reg;   // t within tile
                        stg[(d * 8 + ((r >> 3) ^ (d & 7))) * 8 + (r & 7)] =
                            f2bf(acc[mt][nt][reg] + bv);
                    }
                }
            }
            const size_t vbase = (size_t)(b * Hc + h) * HDc * Tc;
            const int oct = lane & 7;                   // t-chunk
#pragma unroll
            for (int k = 0; k < 8; k++) {
                const int d = (lane >> 3) + k * 8;
                bf16x8 vv = *(const bf16x8*)&stg[(d * 8 + (oct ^ (d & 7))) * 8];
                // 8 lanes cover one full 128-B line per d-row
                *(bf16x8*)&Vtp[vbase + (size_t)d * Tc + t_base + oct * 8] = vv;
            }
        }
    }
}

// ---------------------------------------------------------------------------
// Fused attention. Grid = 1056 blocks:
//   blk 0..31    : global-query rows (full-T, one block per bh).
//   blk 32..1055 : causal, 2-way KEY-SPLIT, DIRECT-L2 FRAGMENT LOADS:
//     R1-R3 all plateaued at 53-59us with identical SQ_LDS_BANK_CONFLICT —
//     the invariant was the LDS-staging + 2-barriers-per-pair skeleton
//     (each __syncthreads drains vmcnt(0) block-wide). Per-bh K/V is 512 KB,
//     L2-resident (4 bh pinned per XCD = 2 MB of 4 MB), and the MFMA
//     fragment layout IS the global layout (the global-query path already
//     does this). Paired h=0/h=1 lanes cover full 128-B lines, so L1
//     (per-CU, shared by the block's waves) keeps L2 traffic ~= one fetch
//     per tile per block — same as staging, with ZERO barriers and zero
//     staging instructions in the main loop. Waves run fully independent
//     until the tiny merge epilogue; latency hides under 16 waves/CU.
//     Each block owns 64 q rows of one bh; waves {0,1} compute EVEN 64-key
//     tiles, waves {2,3} ODD tiles; partials merged via LDS at the end
//     (fixed-max softmax => O,l partials are linear and just add).
// ---------------------------------------------------------------------------
__global__ __launch_bounds__(256) void attn_fused(
    const unsigned short* __restrict__ Q, const unsigned short* __restrict__ K,
    const unsigned short* __restrict__ Vt, const int* __restrict__ ids,
    unsigned short* __restrict__ AO)
{
    __shared__ __align__(16) float smem[8448];   // 33792 B, overlaid per path

    const int tid = threadIdx.x;
    const int lane = tid & 63;
    const int wave = tid >> 6;
    const int c32 = lane & 31;
    const int h = lane >> 5;
    const int blk = blockIdx.x;

    if (blk < 32) {
        // ================= global-query rows =================
        int* s_list = (int*)smem;                 // 64
        int* s_cnt = (int*)smem + 64;
        float* s_accm = smem + 128;               // [4][64][32]
        float* s_lm = s_accm + 8192;              // [4][32]

        const int bh = blk;
        const int b = bh >> 4;
        const int hd = bh & 15;
        const size_t qkbase = (size_t)bh * Tc * HDc;

        if (tid == 0) *s_cnt = 0;
        __syncthreads();
        for (int i = tid; i < Tc; i += 256) {
            int id = ids[b * Tc + i];
            if ((unsigned)(id - 2) <= 5u) {
                int p = atomicAdd(s_cnt, 1);
                if (p < 64) s_list[p] = i;
            }
        }
        __syncthreads();
        const int cnt = min(*s_cnt, 64);

        for (int pass = 0; pass * 32 < cnt; pass++) {
            const int slot = pass * 32 + c32;
            const int row = (slot < cnt) ? s_list[slot] : s_list[0];

            bf16x8 qf[4];
#pragma unroll
            for (int ko = 0; ko < 4; ko++)
                qf[ko] = *(const bf16x8*)&Q[qkbase + (size_t)row * HDc + ko * 16 + h * 8];

            f32x16 acc0 = {}, acc1 = {};
            float lacc = 0.0f;

            for (int it = wave; it < Tc / 64; it += 4) {
                const int t0 = it * 64;
                f32x16 s0 = {}, s1 = {};
#pragma unroll
                for (int ko = 0; ko < 4; ko++) {
                    const int koff = ko * 16 + h * 8;
                    bf16x8 kf0 = *(const bf16x8*)&K[qkbase + (size_t)(t0 + c32) * HDc + koff];
                    bf16x8 kf1 = *(const bf16x8*)&K[qkbase + (size_t)(t0 + 32 + c32) * HDc + koff];
                    s0 = __builtin_amdgcn_mfma_f32_32x32x16_bf16(kf0, qf[ko], s0, 0, 0, 0);
                    s1 = __builtin_amdgcn_mfma_f32_32x32x16_bf16(kf1, qf[ko], s1, 0, 0, 0);
                }
                float v[32];
#pragma unroll
                for (int r = 0; r < 16; r++) { v[r] = s0[r]; v[16 + r] = s1[r]; }
#pragma unroll
                for (int i = 0; i < 32; i++) v[i] = exp2f(v[i] * CEXP);
                unsigned pk[16];
#pragma unroll
                for (int i = 0; i < 16; i++) pk[i] = pack2bf(v[2 * i], v[2 * i + 1]);
#pragma unroll
                for (int st = 1; st < 32; st <<= 1)
#pragma unroll
                    for (int i = 0; i < 32; i += 2 * st) v[i] += v[i + st];
                lacc += v[0];
#pragma unroll
                for (int ko = 0; ko < 4; ko++) {
                    const int a = (ko >> 1) * 8 + (ko & 1) * 4;
                    unsigned keep0 = h ? pk[a + 2] : pk[a + 0];
                    unsigned keep1 = h ? pk[a + 3] : pk[a + 1];
                    unsigned send0 = h ? pk[a + 0] : pk[a + 2];
                    unsigned send1 = h ? pk[a + 1] : pk[a + 3];
                    unsigned recv0 = (unsigned)__shfl_xor((int)send0, 32);
                    unsigned recv1 = (unsigned)__shfl_xor((int)send1, 32);
                    union { bf16x8 v8; unsigned u[4]; } pf;
                    pf.u[0] = h ? recv0 : keep0;
                    pf.u[1] = h ? recv1 : keep1;
                    pf.u[2] = h ? keep0 : recv0;
                    pf.u[3] = h ? keep1 : recv1;
                    const int oct = ko * 2 + h;
                    bf16x8 vf0 = *(const bf16x8*)&Vt[qkbase + (size_t)c32 * Tc + t0 + oct * 8];
                    bf16x8 vf1 = *(const bf16x8*)&Vt[qkbase + (size_t)(32 + c32) * Tc + t0 + oct * 8];
                    acc0 = __builtin_amdgcn_mfma_f32_32x32x16_bf16(vf0, pf.v8, acc0, 0, 0, 0);
                    acc1 = __builtin_amdgcn_mfma_f32_32x32x16_bf16(vf1, pf.v8, acc1, 0, 0, 0);
                }
            }

            const float lfull = lacc + __shfl_xor(lacc, 32);
            if (h == 0) s_lm[wave * 32 + c32] = lfull;
#pragma unroll
            for (int r = 0; r < 16; r++) {
                const int d = (r & 3) + 8 * (r >> 2) + 4 * h;
                s_accm[(wave * 64 + d) * 32 + c32] = acc0[r];
                s_accm[(wave * 64 + 32 + d) * 32 + c32] = acc1[r];
            }
            __syncthreads();
            for (int i = tid; i < 2048; i += 256) {
                const int sl = i >> 6, d = i & 63;
                if (pass * 32 + sl < cnt) {
                    const float o = s_accm[(0 * 64 + d) * 32 + sl] + s_accm[(1 * 64 + d) * 32 + sl] +
                                    s_accm[(2 * 64 + d) * 32 + sl] + s_accm[(3 * 64 + d) * 32 + sl];
                    const float lt = s_lm[sl] + s_lm[32 + sl] + s_lm[64 + sl] + s_lm[96 + sl];
                    const int qrow = s_list[pass * 32 + sl];
                    AO[((size_t)(b * Tc + qrow)) * Dc + hd * HDc + d] = f2bf(o / lt);
                }
            }
            __syncthreads();
        }
        return;
    }

    // ===== causal path: direct-L2 fragment loads, barrier-free main loop =====
    const int idx = blk - 32;                      // 0..1023
    const int bh = (idx & 7) + 8 * ((idx >> 3) & 3);   // 4 bh per XCD
    const int b = bh >> 4;
    const int hd = bh & 15;
    // weight index -> j so stride-8 samples {w, w+8, w+16, w+24} spread the
    // heavy q-tiles evenly across the dispatch order.
    const int w = idx >> 5;                        // 0..31
    const int u = w & 7, tq = w >> 3;
    const int j = (tq == 0) ? u : (tq == 1) ? 31 - u : (tq == 2) ? 8 + u : 23 - u;
    const int qb0 = j * 64;
    const int nT = j + 1;                          // 64-key tiles in [0, qb0+64)
    const int grp = wave >> 1;                     // 0: even tiles, 1: odd
    const int wq0 = qb0 + (wave & 1) * 32;         // wave's 32 q rows
    const size_t qkbase = (size_t)bh * Tc * HDc;
    const int q = wq0 + c32;

    // Q B-fragments (whole kernel): B[k=hd=ko*16+h*8+j][n=q=c32]
    bf16x8 qf[4];
#pragma unroll
    for (int ko = 0; ko < 4; ko++)
        qf[ko] = *(const bf16x8*)&Q[qkbase + (size_t)q * HDc + ko * 16 + h * 8];

    const int myid = ids[b * Tc + q];
    const bool gr = ((unsigned)(myid - 2) <= 5u);  // global row: store suppressed

    f32x16 acc0 = {}, acc1 = {};
    float lacc = 0.0f;

    for (int tt = grp; tt < nT; tt += 2) {
        const int t0 = tt * 64;

        // --- K fragments direct from L1/L2 (paired lanes cover full lines)
        bf16x8 kf[8];
#pragma unroll
        for (int ko = 0; ko < 4; ko++) {
            const int koff = ko * 16 + h * 8;
            kf[2 * ko]     = *(const bf16x8*)&K[qkbase + (size_t)(t0 + c32) * HDc + koff];
            kf[2 * ko + 1] = *(const bf16x8*)&K[qkbase + (size_t)(t0 + 32 + c32) * HDc + koff];
        }
        // --- scores S^T[key][q]: 2 key-subtiles of 32, contraction 64
        f32x16 s0 = {}, s1 = {};
#pragma unroll
        for (int ko = 0; ko < 4; ko++) {
            s0 = __builtin_amdgcn_mfma_f32_32x32x16_bf16(kf[2 * ko], qf[ko], s0, 0, 0, 0);
            s1 = __builtin_amdgcn_mfma_f32_32x32x16_bf16(kf[2 * ko + 1], qf[ko], s1, 0, 0, 0);
        }

        // --- fixed-max softmax: p = exp2(s*CEXP)
        float v[32];
#pragma unroll
        for (int r = 0; r < 16; r++) { v[r] = s0[r]; v[16 + r] = s1[r]; }
#pragma unroll
        for (int i = 0; i < 32; i++) v[i] = exp2f(v[i] * CEXP);

        // --- V fragments: issue now, latency hides under mask/pack/tree
        bf16x8 vf[8];
#pragma unroll
        for (int ko = 0; ko < 4; ko++) {
            const int oct = ko * 2 + h;
            vf[2 * ko]     = *(const bf16x8*)&Vt[qkbase + (size_t)c32 * Tc + t0 + oct * 8];
            vf[2 * ko + 1] = *(const bf16x8*)&Vt[qkbase + (size_t)(32 + c32) * Tc + t0 + oct * 8];
        }

        const bool needMask = (t0 + 63 > wq0);     // wave-uniform (diag tile)
        if (needMask) {
            const int thr = wq0 + c32 - t0 - 4 * h;
#pragma unroll
            for (int kt = 0; kt < 2; kt++)
#pragma unroll
                for (int r = 0; r < 16; r++) {
                    const int ckr = kt * 32 + (r & 3) + 8 * (r >> 2);
                    v[kt * 16 + r] = (ckr <= thr) ? v[kt * 16 + r] : 0.0f;
                }
        }

        unsigned pk[16];
#pragma unroll
        for (int i = 0; i < 16; i++) pk[i] = pack2bf(v[2 * i], v[2 * i + 1]);

        // l accumulation: depth-5 pairwise tree, no cross-lane op
#pragma unroll
        for (int st = 1; st < 32; st <<= 1)
#pragma unroll
            for (int i = 0; i < 32; i += 2 * st) v[i] += v[i + st];
        lacc += v[0];

        // --- PV: O^T += V^T x P^T
#pragma unroll
        for (int ko = 0; ko < 4; ko++) {
            const int a = (ko >> 1) * 8 + (ko & 1) * 4;
            unsigned keep0 = h ? pk[a + 2] : pk[a + 0];
            unsigned keep1 = h ? pk[a + 3] : pk[a + 1];
            unsigned send0 = h ? pk[a + 0] : pk[a + 2];
            unsigned send1 = h ? pk[a + 1] : pk[a + 3];
            unsigned recv0 = (unsigned)__shfl_xor((int)send0, 32);
            unsigned recv1 = (unsigned)__shfl_xor((int)send1, 32);
            union { bf16x8 v8; unsigned u[4]; } pf;
            pf.u[0] = h ? recv0 : keep0;
            pf.u[1] = h ? recv1 : keep1;
            pf.u[2] = h ? keep0 : recv0;
            pf.u[3] = h ? keep1 : recv1;
            acc0 = __builtin_amdgcn_mfma_f32_32x32x16_bf16(vf[2 * ko], pf.v8, acc0, 0, 0, 0);
            acc1 = __builtin_amdgcn_mfma_f32_32x32x16_bf16(vf[2 * ko + 1], pf.v8, acc1, 0, 0, 0);
        }
    }

    // --- merge key-split partials: wave 2->0, 3->1 via LDS ([r][lane]: no
    // bank conflicts), then h-halves of l, then store.
    __syncthreads();
    float* mrg = smem + (wave & 1) * 2176;         // 2 pairs x 2176 f32
    if (wave >= 2) {
#pragma unroll
        for (int r = 0; r < 16; r++) {
            mrg[r * 64 + lane] = acc0[r];
            mrg[(16 + r) * 64 + lane] = acc1[r];
        }
        mrg[2048 + lane] = lacc;
    }
    __syncthreads();
    if (wave >= 2) return;
#pragma unroll
    for (int r = 0; r < 16; r++) {
        acc0[r] += mrg[r * 64 + lane];
        acc1[r] += mrg[(16 + r) * 64 + lane];
    }
    lacc += mrg[2048 + lane];

    const float l = lacc + __shfl_xor(lacc, 32);
    if (!gr) {
        const float inv = 1.0f / l;
        unsigned short* dst = &AO[((size_t)(b * Tc + q)) * Dc + hd * HDc];
#pragma unroll
        for (int i = 0; i < 8; i++) {
            const int r = 2 * i;
            const int d = (r & 3) + 8 * (r >> 2) + 4 * h;
            *(unsigned*)&dst[d]      = pack2bf(acc0[r] * inv, acc0[r + 1] * inv);
            *(unsigned*)&dst[32 + d] = pack2bf(acc1[r] * inv, acc1[r + 1] * inv);
        }
    }
}

// ---------------------------------------------------------------------------
extern "C" void kernel_launch(void* const* d_in, const int* in_sizes, int n_in,
                              void* d_out, int out_size, void* d_ws, size_t ws_size,
                              hipStream_t stream)
{
    const float* x    = (const float*)d_in[0];
    const int*   ids  = (const int*)d_in[1];
    const float* Wqkv = (const float*)d_in[2];
    const float* bqkv = (const float*)d_in[3];
    const float* Wout = (const float*)d_in[4];
    const float* bout = (const float*)d_in[5];
    float* out = (float*)d_out;

    const size_t TEN = (size_t)Bc * Hc * Tc * HDc;   // 4,194,304 elements
    unsigned short* xb    = (unsigned short*)d_ws;            // 4.2M us
    unsigned short* wqkvb = xb + 4194304;                     // 3.1M us
    unsigned short* woutb = wqkvb + 3145728;                  // 1.0M us
    float2* ropeTab       = (float2*)(woutb + 1048576);       // 64K float2
    unsigned short* Qb    = (unsigned short*)(ropeTab + 65536);
    unsigned short* Kb    = Qb + TEN;
    unsigned short* Vtb   = Kb + TEN;
    unsigned short* AOb   = Vtb + TEN;                        // ~51 MB total

    // 0. fp32 -> bf16 conversions + RoPE table
    convert_bf16<<<8192, 256, 0, stream>>>(x, Wqkv, Wout, xb, wqkvb, woutb,
                                           ropeTab);
    // 1. QKV projection (MFMA) + fused RoPE -> bf16 Q/K [b,h,t,d], V^T [b,h,d,t]
    dim3 g1(3072 / 128, 4096 / 128);
    gemm_mfma<1><<<g1, 256, 0, stream>>>(xb, wqkvb, bqkv, nullptr,
                                         Qb, Kb, Vtb, ropeTab, 4096, 3072, 1024);
    // 2. attention (barrier-free direct-L2 causal + global path) -> bf16 AO
    attn_fused<<<1056, 256, 0, stream>>>(Qb, Kb, Vtb, ids, AOb);
    // 3. output projection (MFMA, fp32 out)
    dim3 g4(1024 / 128, 4096 / 128);
    gemm_mfma<0><<<g4, 256, 0, stream>>>(AOb, woutb, bout, out,
                                         nullptr, nullptr, nullptr, nullptr,
                                         4096, 1024, 1024);
}

// Round 5
// 208.621 us; speedup vs baseline: 1.1271x; 1.1271x over previous
//
#include <hip/hip_runtime.h>
#include <math.h>

// Problem constants
#define Bc 2
#define Tc 2048
#define Dc 1024
#define Hc 16
#define HDc 64
// M = B*T = 4096, QKV N = 3072, K = 1024

typedef __attribute__((ext_vector_type(8))) short bf16x8;
typedef __attribute__((ext_vector_type(4))) float f32x4;
typedef __attribute__((ext_vector_type(16))) float f32x16;

__device__ __forceinline__ unsigned short f2bf(float f) {
    union { float f; unsigned int u; } v; v.f = f;
    unsigned int r = (v.u + 0x7FFFu + ((v.u >> 16) & 1u)) >> 16;   // RNE
    return (unsigned short)r;
}
// pack two fp32 -> bf16x2 dword (round-nearest, ties up): 3 VALU
__device__ __forceinline__ unsigned pack2bf(float a, float b) {
    unsigned au = __float_as_uint(a) + 0x8000u;
    unsigned bu = __float_as_uint(b) + 0x8000u;
    return __builtin_amdgcn_perm(bu, au, 0x07060302u);
}

// async global->LDS, 16 B per lane. LDS dest is WAVE-UNIFORM base + lane*16.
__device__ __forceinline__ void gload_lds16(const unsigned short* g,
                                            unsigned short* l) {
    __builtin_amdgcn_global_load_lds(
        (const __attribute__((address_space(1))) unsigned int*)g,
        (__attribute__((address_space(3))) unsigned int*)l,
        16, 0, 0);
}

// exp scale: 1/sqrt(64) * log2(e)  (fixed-max softmax: p = exp2(s*CEXP))
#define CEXP 0.1803368801111204f

// ---------------------------------------------------------------------------
// fp32 -> bf16 conversion for x, W_qkv, W_out + RoPE cos/sin table fill.
// ---------------------------------------------------------------------------
__global__ __launch_bounds__(256) void convert_bf16(
    const float* __restrict__ x, const float* __restrict__ wqkv,
    const float* __restrict__ wout,
    unsigned short* __restrict__ xb, unsigned short* __restrict__ wqkvb,
    unsigned short* __restrict__ woutb, float2* __restrict__ ropeTab)
{
    const int gid = blockIdx.x * 256 + threadIdx.x;
    // RoPE table: 2048 x 32 entries (cos, sin), angle = t * 10000^(-i/32)
    if (gid < Tc * 32) {
        const int t = gid >> 5, i = gid & 31;
        const float freq = exp2f((float)i * -0.4152410118609203f);
        const float ang = (float)t * freq;
        ropeTab[gid] = make_float2(cosf(ang), sinf(ang));
    }
    const int i = gid * 4;                        // 8,388,608 floats total
    const float* src; unsigned short* dst; int off;
    if (i < 4194304)      { src = x;    dst = xb;    off = i; }
    else if (i < 7340032) { src = wqkv; dst = wqkvb; off = i - 4194304; }
    else                  { src = wout; dst = woutb; off = i - 7340032; }
    float4 v = *(const float4*)&src[off];
    ushort4 o;
    o.x = f2bf(v.x); o.y = f2bf(v.y); o.z = f2bf(v.z); o.w = f2bf(v.w);
    *(ushort4*)&dst[off] = o;
}

// ---------------------------------------------------------------------------
// bf16 MFMA GEMM:  C[M,N] = A[M,K] @ W[N,K]^T + bias[N]
// BM=BN=128, BK=64, 256 thr = 4 waves (2x2), 64x64 per wave.
// Staging: async global_load_lds width=16 (linear LDS dest), with the global
// source oct PRE-SWIZZLED so LDS[r][o] = G[r][o ^ (r&7)] -> fragment reads
// (unchanged XOR addressing) stay 2-way-conflict-free (free per m136).
// MODE 0: fp32 C row-major + bias
// MODE 1: bf16 scatter with FUSED RoPE on Q,K -> [b,h,t,d]; V -> [b,h,d,t].
// ---------------------------------------------------------------------------
template <int MODE>
__global__ __launch_bounds__(256) void gemm_mfma(
    const unsigned short* __restrict__ A, const unsigned short* __restrict__ W,
    const float* __restrict__ bias, float* __restrict__ C,
    unsigned short* __restrict__ Qp, unsigned short* __restrict__ Kp,
    unsigned short* __restrict__ Vtp, const float2* __restrict__ ropeTab,
    int M, int N, int K)
{
    __shared__ unsigned short Apk[128 * 8 * 8];
    __shared__ unsigned short Bpk[128 * 8 * 8];

    const int tid = threadIdx.x;
    const int lane = tid & 63;
    const int wave = tid >> 6;
    const int quad = lane >> 4;
    const int c = lane & 15;
    const int wm = wave >> 1;
    const int wn = wave & 1;
    const int m0 = blockIdx.y * 128;
    const int n0 = blockIdx.x * 128;

    f32x4 acc[4][4];
#pragma unroll
    for (int mt = 0; mt < 4; mt++)
#pragma unroll
        for (int nt = 0; nt < 4; nt++) acc[mt][nt] = (f32x4){0.f, 0.f, 0.f, 0.f};

    // staging: wave-load of 1 KB covers 8 rows x 8 octs. lane -> (row, oct):
    // row_in_chunk = lane>>3, lds oct = lane&7 (fixed by HW linear layout).
    // source oct = (lane&7) ^ (r&7); since r&7 == lane>>3 for all chunks,
    // it's the lane-only constant below.
    const int lrow = lane >> 3;
    const int srcoct = (lane & 7) ^ lrow;

    for (int k0 = 0; k0 < K; k0 += 64) {
        __syncthreads();                       // prior tile's ds_reads done
#pragma unroll
        for (int i = 0; i < 4; i++) {
            const int r = wave * 32 + i * 8 + lrow;
            gload_lds16(&A[(size_t)(m0 + r) * K + k0 + srcoct * 8],
                        &Apk[(wave * 32 + i * 8) * 64]);
            gload_lds16(&W[(size_t)(n0 + r) * K + k0 + srcoct * 8],
                        &Bpk[(wave * 32 + i * 8) * 64]);
        }
        __syncthreads();                       // drains vmcnt(0): tile ready
#pragma unroll
        for (int ko = 0; ko < 2; ko++) {
            bf16x8 af[4], bf[4];
#pragma unroll
            for (int mt = 0; mt < 4; mt++) {
                const int m = wm * 64 + mt * 16 + c;
                af[mt] = *(const bf16x8*)&Apk[(m * 8 + ((ko * 4 + quad) ^ (m & 7))) * 8];
            }
#pragma unroll
            for (int nt = 0; nt < 4; nt++) {
                const int n = wn * 64 + nt * 16 + c;
                bf[nt] = *(const bf16x8*)&Bpk[(n * 8 + ((ko * 4 + quad) ^ (n & 7))) * 8];
            }
#pragma unroll
            for (int mt = 0; mt < 4; mt++)
#pragma unroll
                for (int nt = 0; nt < 4; nt++)
                    acc[mt][nt] = __builtin_amdgcn_mfma_f32_16x16x32_bf16(
                        af[mt], bf[nt], acc[mt][nt], 0, 0, 0);
        }
    }

    if (MODE == 0) {
#pragma unroll
        for (int mt = 0; mt < 4; mt++) {
            const int m = m0 + wm * 64 + mt * 16 + quad * 4;
#pragma unroll
            for (int nt = 0; nt < 4; nt++) {
                const int n = n0 + wn * 64 + nt * 16 + c;
                const float bv = bias[n];
#pragma unroll
                for (int reg = 0; reg < 4; reg++)
                    C[(size_t)(m + reg) * N + n] = acc[mt][nt][reg] + bv;
            }
        }
    } else {
        const int n_wave = n0 + wn * 64;          // 64-aligned -> one head/wave
        const int which = n_wave >> 10;           // 0=q,1=k,2=v (block-uniform)
        const int h = (n_wave >> 6) & 15;
        const int b = m0 >> 11;
        const int t_base = (m0 & 2047) + wm * 64;

        __syncthreads();   // all MFMA LDS reads done; reuse Apk/Bpk as staging
        // per-wave 8-KB staging region (wave-private; DS ops in-order per wave)
        unsigned short* stg = ((wave < 2) ? Apk : Bpk) + (wave & 1) * 4096;

        if (which < 2) {
            // ---- Q/K with fused RoPE: rotate -> LDS tile -> coalesced store
            unsigned short* dst = (which == 0) ? Qp : Kp;
#pragma unroll
            for (int mt = 0; mt < 4; mt++) {
#pragma unroll
                for (int nt = 0; nt < 2; nt++) {
                    const int i1 = nt * 16 + c;            // rotary index 0..31
                    const float bv1 = bias[n_wave + i1];
                    const float bv2 = bias[n_wave + 32 + i1];
#pragma unroll
                    for (int reg = 0; reg < 4; reg++) {
                        const int row = mt * 16 + quad * 4 + reg;
                        const float2 cs = ropeTab[(t_base + row) * 32 + i1];
                        const float x1 = acc[mt][nt][reg] + bv1;
                        const float x2 = acc[mt][nt + 2][reg] + bv2;
                        const int col2 = 32 + i1;
                        stg[(row * 8 + ((i1 >> 3) ^ (row & 7))) * 8 + (i1 & 7)] =
                            f2bf(x1 * cs.x - x2 * cs.y);
                        stg[(row * 8 + ((col2 >> 3) ^ (row & 7))) * 8 + (col2 & 7)] =
                            f2bf(x1 * cs.y + x2 * cs.x);
                    }
                }
            }
            // tile [t_base..t_base+63][0..63] is 8 KB CONTIGUOUS in Q/K
            const size_t obase = ((size_t)(b * Hc + h) * Tc + t_base) * HDc;
            const int oct = lane & 7;
#pragma unroll
            for (int k = 0; k < 8; k++) {
                const int f = lane * 8 + k * 512;       // flat ushort offset
                const int row = f >> 6;
                bf16x8 vv = *(const bf16x8*)&stg[(row * 8 + (oct ^ (row & 7))) * 8];
                *(bf16x8*)&dst[obase + f] = vv;         // 64 lanes x 16 B = 1 KB
            }
        } else {
            // ---- V: stage transposed tile [d][t], store full 128-B d-rows
#pragma unroll
            for (int mt = 0; mt < 4; mt++) {
#pragma unroll
                for (int nt = 0; nt < 4; nt++) {
                    const int d = nt * 16 + c;
                    const float bv = bias[n_wave + d];
#pragma unroll
                    for (int reg = 0; reg < 4; reg++) {
                        const int r = mt * 16 + quad * 4 + reg;   // t within tile
                        stg[(d * 8 + ((r >> 3) ^ (d & 7))) * 8 + (r & 7)] =
                            f2bf(acc[mt][nt][reg] + bv);
                    }
                }
            }
            const size_t vbase = (size_t)(b * Hc + h) * HDc * Tc;
            const int oct = lane & 7;                   // t-chunk
#pragma unroll
            for (int k = 0; k < 8; k++) {
                const int d = (lane >> 3) + k * 8;
                bf16x8 vv = *(const bf16x8*)&stg[(d * 8 + (oct ^ (d & 7))) * 8];
                // 8 lanes cover one full 128-B line per d-row
                *(bf16x8*)&Vtp[vbase + (size_t)d * Tc + t_base + oct * 8] = vv;
            }
        }
    }
}

// ---------------------------------------------------------------------------
// Fused attention. Grid = 1056 blocks:
//   blk 0..31    : global-query rows (full-T, one block per bh).
//   blk 32..1055 : causal, 2-way KEY-SPLIT (fixed-max softmax => O,l partials
//     are linear and just add):
//       each block owns 64 q rows of one bh; waves {0,1} compute EVEN 64-key
//       tiles, waves {2,3} ODD tiles (same q rows); partials merged via LDS.
//     R2 schedule (best measured 52.8us): stage K+V pair -> barrier ->
//     compute, 2 barriers/pair, gload_lds staging.
//     NATURAL VGPR (no min-waves bound): R2's (256,4) forced VGPR=64 ->
//     ~14 MB scratch spills (WRITE 8.4->22.5 MB); ~112 VGPR still gives
//     4 blocks/CU (LDS 33KB -> 4 blocks; VGPR<=128 -> 4 waves/SIMD).
//     R4 lesson: do NOT drop LDS staging — direct fragment loads from
//     global scatter 32 lines/instruction (K: 128B-stride, Vt: 4KB-stride)
//     and serialize the VMEM pipe (87us). LDS staging IS the coalescer.
// ---------------------------------------------------------------------------
__global__ __launch_bounds__(256) void attn_fused(
    const unsigned short* __restrict__ Q, const unsigned short* __restrict__ K,
    const unsigned short* __restrict__ Vt, const int* __restrict__ ids,
    unsigned short* __restrict__ AO)
{
    __shared__ __align__(16) float smem[8448];   // 33792 B, overlaid per path

    const int tid = threadIdx.x;
    const int lane = tid & 63;
    const int wave = tid >> 6;
    const int c32 = lane & 31;
    const int h = lane >> 5;
    const int blk = blockIdx.x;

    if (blk < 32) {
        // ================= global-query rows =================
        int* s_list = (int*)smem;                 // 64
        int* s_cnt = (int*)smem + 64;
        float* s_accm = smem + 128;               // [4][64][32]
        float* s_lm = s_accm + 8192;              // [4][32]

        const int bh = blk;
        const int b = bh >> 4;
        const int hd = bh & 15;
        const size_t qkbase = (size_t)bh * Tc * HDc;

        if (tid == 0) *s_cnt = 0;
        __syncthreads();
        for (int i = tid; i < Tc; i += 256) {
            int id = ids[b * Tc + i];
            if ((unsigned)(id - 2) <= 5u) {
                int p = atomicAdd(s_cnt, 1);
                if (p < 64) s_list[p] = i;
            }
        }
        __syncthreads();
        const int cnt = min(*s_cnt, 64);

        for (int pass = 0; pass * 32 < cnt; pass++) {
            const int slot = pass * 32 + c32;
            const int row = (slot < cnt) ? s_list[slot] : s_list[0];

            bf16x8 qf[4];
#pragma unroll
            for (int ko = 0; ko < 4; ko++)
                qf[ko] = *(const bf16x8*)&Q[qkbase + (size_t)row * HDc + ko * 16 + h * 8];

            f32x16 acc0 = {}, acc1 = {};
            float lacc = 0.0f;

            for (int it = wave; it < Tc / 64; it += 4) {
                const int t0 = it * 64;
                f32x16 s0 = {}, s1 = {};
#pragma unroll
                for (int ko = 0; ko < 4; ko++) {
                    const int koff = ko * 16 + h * 8;
                    bf16x8 kf0 = *(const bf16x8*)&K[qkbase + (size_t)(t0 + c32) * HDc + koff];
                    bf16x8 kf1 = *(const bf16x8*)&K[qkbase + (size_t)(t0 + 32 + c32) * HDc + koff];
                    s0 = __builtin_amdgcn_mfma_f32_32x32x16_bf16(kf0, qf[ko], s0, 0, 0, 0);
                    s1 = __builtin_amdgcn_mfma_f32_32x32x16_bf16(kf1, qf[ko], s1, 0, 0, 0);
                }
                float v[32];
#pragma unroll
                for (int r = 0; r < 16; r++) { v[r] = s0[r]; v[16 + r] = s1[r]; }
#pragma unroll
                for (int i = 0; i < 32; i++) v[i] = exp2f(v[i] * CEXP);
                unsigned pk[16];
#pragma unroll
                for (int i = 0; i < 16; i++) pk[i] = pack2bf(v[2 * i], v[2 * i + 1]);
#pragma unroll
                for (int st = 1; st < 32; st <<= 1)
#pragma unroll
                    for (int i = 0; i < 32; i += 2 * st) v[i] += v[i + st];
                lacc += v[0];
#pragma unroll
                for (int ko = 0; ko < 4; ko++) {
                    const int a = (ko >> 1) * 8 + (ko & 1) * 4;
                    unsigned keep0 = h ? pk[a + 2] : pk[a + 0];
                    unsigned keep1 = h ? pk[a + 3] : pk[a + 1];
                    unsigned send0 = h ? pk[a + 0] : pk[a + 2];
                    unsigned send1 = h ? pk[a + 1] : pk[a + 3];
                    unsigned recv0 = (unsigned)__shfl_xor((int)send0, 32);
                    unsigned recv1 = (unsigned)__shfl_xor((int)send1, 32);
                    union { bf16x8 v8; unsigned u[4]; } pf;
                    pf.u[0] = h ? recv0 : keep0;
                    pf.u[1] = h ? recv1 : keep1;
                    pf.u[2] = h ? keep0 : recv0;
                    pf.u[3] = h ? keep1 : recv1;
                    const int oct = ko * 2 + h;
                    bf16x8 vf0 = *(const bf16x8*)&Vt[qkbase + (size_t)c32 * Tc + t0 + oct * 8];
                    bf16x8 vf1 = *(const bf16x8*)&Vt[qkbase + (size_t)(32 + c32) * Tc + t0 + oct * 8];
                    acc0 = __builtin_amdgcn_mfma_f32_32x32x16_bf16(vf0, pf.v8, acc0, 0, 0, 0);
                    acc1 = __builtin_amdgcn_mfma_f32_32x32x16_bf16(vf1, pf.v8, acc1, 0, 0, 0);
                }
            }

            const float lfull = lacc + __shfl_xor(lacc, 32);
            if (h == 0) s_lm[wave * 32 + c32] = lfull;
#pragma unroll
            for (int r = 0; r < 16; r++) {
                const int d = (r & 3) + 8 * (r >> 2) + 4 * h;
                s_accm[(wave * 64 + d) * 32 + c32] = acc0[r];
                s_accm[(wave * 64 + 32 + d) * 32 + c32] = acc1[r];
            }
            __syncthreads();
            for (int i = tid; i < 2048; i += 256) {
                const int sl = i >> 6, d = i & 63;
                if (pass * 32 + sl < cnt) {
                    const float o = s_accm[(0 * 64 + d) * 32 + sl] + s_accm[(1 * 64 + d) * 32 + sl] +
                                    s_accm[(2 * 64 + d) * 32 + sl] + s_accm[(3 * 64 + d) * 32 + sl];
                    const float lt = s_lm[sl] + s_lm[32 + sl] + s_lm[64 + sl] + s_lm[96 + sl];
                    const int qrow = s_list[pass * 32 + sl];
                    AO[((size_t)(b * Tc + qrow)) * Dc + hd * HDc + d] = f2bf(o / lt);
                }
            }
            __syncthreads();
        }
        return;
    }

    // ============ causal path: 2-way key-split + fixed-max softmax ============
    unsigned short* KV = (unsigned short*)smem;
    unsigned short* Ke = KV;                       // even-tile K (8 KB)
    unsigned short* Ko = KV + 4096;                // odd-tile  K
    unsigned short* Ve = KV + 8192;                // even-tile V^T
    unsigned short* Vo = KV + 12288;               // odd-tile  V^T

    const int idx = blk - 32;                      // 0..1023
    const int bh = (idx & 7) + 8 * ((idx >> 3) & 3);   // 4 bh per XCD
    const int b = bh >> 4;
    const int hd = bh & 15;
    // weight index -> j so stride-8 samples {w, w+8, w+16, w+24} (one CU's 4
    // resident blocks) give j = {u, 31-u, 8+u, 23-u}: nTiles sum == 66 const.
    const int w = idx >> 5;                        // 0..31
    const int u = w & 7, tq = w >> 3;
    const int j = (tq == 0) ? u : (tq == 1) ? 31 - u : (tq == 2) ? 8 + u : 23 - u;
    const int qb0 = j * 64;
    const int nT = j + 1;                          // 64-key tiles in [0, qb0+64)
    const int wq0 = qb0 + (wave & 1) * 32;         // wave's 32 q rows
    const size_t qkbase = (size_t)bh * Tc * HDc;
    const int q = wq0 + c32;

    // Q B-fragments (whole kernel): B[k=hd=ko*16+h*8+j][n=q=c32]
    bf16x8 qf[4];
#pragma unroll
    for (int ko = 0; ko < 4; ko++)
        qf[ko] = *(const bf16x8*)&Q[qkbase + (size_t)q * HDc + ko * 16 + h * 8];

    const int myid = ids[b * Tc + q];
    const bool gr = ((unsigned)(myid - 2) <= 5u);  // global row: store suppressed

    f32x16 acc0 = {}, acc1 = {};
    float lacc = 0.0f;

    // staging constants (global_load_lds: linear LDS, pre-swizzled source)
    const int lrow = lane >> 3;                    // 0..7
    const int srcoct = (lane & 7) ^ lrow;          // source oct for this lane
    const int jb = wave * 2;                       // wave's 1-KB chunk base

    auto stageK = [&](int t0, unsigned short* buf) {
#pragma unroll
        for (int i = 0; i < 2; i++) {
            const int jj = jb + i;                 // 0..7 (8 x 1 KB = 8 KB)
            const int row = jj * 8 + lrow;         // key row 0..63
            gload_lds16(&K[qkbase + (size_t)(t0 + row) * HDc + srcoct * 8],
                        &buf[jj * 512]);
        }
    };
    auto stageV = [&](int t0, unsigned short* buf) {
#pragma unroll
        for (int i = 0; i < 2; i++) {
            const int jj = jb + i;
            const int d = jj * 8 + lrow;           // d row 0..63
            gload_lds16(&Vt[qkbase + (size_t)d * Tc + t0 + srcoct * 8],
                        &buf[jj * 512]);
        }
    };

    auto computeT = [&](int t0, const unsigned short* Kb, const unsigned short* Vb) {
        // --- scores S^T[key][q]: 2 key-tiles of 32, contraction 64 = 4 MFMAs
        f32x16 s0 = {}, s1 = {};
#pragma unroll
        for (int ko = 0; ko < 4; ko++) {
            const int oct = ko * 2 + h;
            const int k0i = c32;
            const int k1i = 32 + c32;
            bf16x8 kf0 = *(const bf16x8*)&Kb[(k0i * 8 + (oct ^ (k0i & 7))) * 8];
            bf16x8 kf1 = *(const bf16x8*)&Kb[(k1i * 8 + (oct ^ (k1i & 7))) * 8];
            s0 = __builtin_amdgcn_mfma_f32_32x32x16_bf16(kf0, qf[ko], s0, 0, 0, 0);
            s1 = __builtin_amdgcn_mfma_f32_32x32x16_bf16(kf1, qf[ko], s1, 0, 0, 0);
        }

        // --- fixed-max softmax: p = exp2(s*CEXP), no chains, no cross-lane
        float v[32];
#pragma unroll
        for (int r = 0; r < 16; r++) { v[r] = s0[r]; v[16 + r] = s1[r]; }
#pragma unroll
        for (int i = 0; i < 32; i++) v[i] = exp2f(v[i] * CEXP);

        const bool needMask = (t0 + 63 > wq0);     // wave-uniform (diag tile)
        if (needMask) {
            const int thr = wq0 + c32 - t0 - 4 * h;
#pragma unroll
            for (int kt = 0; kt < 2; kt++)
#pragma unroll
                for (int r = 0; r < 16; r++) {
                    const int ckr = kt * 32 + (r & 3) + 8 * (r >> 2);
                    v[kt * 16 + r] = (ckr <= thr) ? v[kt * 16 + r] : 0.0f;
                }
        }

        unsigned pk[16];
#pragma unroll
        for (int i = 0; i < 16; i++) pk[i] = pack2bf(v[2 * i], v[2 * i + 1]);

        // l accumulation: depth-5 pairwise tree, no cross-lane op
#pragma unroll
        for (int st = 1; st < 32; st <<= 1)
#pragma unroll
            for (int i = 0; i < 32; i += 2 * st) v[i] += v[i + st];
        lacc += v[0];

        // --- PV: O^T += V^T x P^T
#pragma unroll
        for (int ko = 0; ko < 4; ko++) {
            const int a = (ko >> 1) * 8 + (ko & 1) * 4;
            unsigned keep0 = h ? pk[a + 2] : pk[a + 0];
            unsigned keep1 = h ? pk[a + 3] : pk[a + 1];
            unsigned send0 = h ? pk[a + 0] : pk[a + 2];
            unsigned send1 = h ? pk[a + 1] : pk[a + 3];
            unsigned recv0 = (unsigned)__shfl_xor((int)send0, 32);
            unsigned recv1 = (unsigned)__shfl_xor((int)send1, 32);
            union { bf16x8 v8; unsigned u[4]; } pf;
            pf.u[0] = h ? recv0 : keep0;
            pf.u[1] = h ? recv1 : keep1;
            pf.u[2] = h ? keep0 : recv0;
            pf.u[3] = h ? keep1 : recv1;
            const int oct = ko * 2 + h;
            const int d0 = c32, d1 = 32 + c32;
            bf16x8 vf0 = *(const bf16x8*)&Vb[(d0 * 8 + (oct ^ (d0 & 7))) * 8];
            bf16x8 vf1 = *(const bf16x8*)&Vb[(d1 * 8 + (oct ^ (d1 & 7))) * 8];
            acc0 = __builtin_amdgcn_mfma_f32_32x32x16_bf16(vf0, pf.v8, acc0, 0, 0, 0);
            acc1 = __builtin_amdgcn_mfma_f32_32x32x16_bf16(vf1, pf.v8, acc1, 0, 0, 0);
        }
    };

    // K-loop over tile pairs: stage (even,odd) -> group A even, group B odd
    for (int tp = 0; tp < nT; tp += 2) {
        __syncthreads();                           // prior pair's reads done
        stageK(tp * 64, Ke);
        stageV(tp * 64, Ve);
        const bool has2 = (tp + 1) < nT;
        if (has2) {
            stageK((tp + 1) * 64, Ko);
            stageV((tp + 1) * 64, Vo);
        }
        __syncthreads();                           // drains vmcnt: pair ready
        if ((wave >> 1) == 0) computeT(tp * 64, Ke, Ve);
        else if (has2) computeT((tp + 1) * 64, Ko, Vo);
    }

    // --- merge key-split partials: wave 2->0, 3->1 via LDS ([r][lane]: no
    // bank conflicts), then h-halves of l, then store.
    __syncthreads();
    float* mrg = smem + (wave & 1) * 2176;         // 2 pairs x 2176 f32
    if (wave >= 2) {
#pragma unroll
        for (int r = 0; r < 16; r++) {
            mrg[r * 64 + lane] = acc0[r];
            mrg[(16 + r) * 64 + lane] = acc1[r];
        }
        mrg[2048 + lane] = lacc;
    }
    __syncthreads();
    if (wave >= 2) return;
#pragma unroll
    for (int r = 0; r < 16; r++) {
        acc0[r] += mrg[r * 64 + lane];
        acc1[r] += mrg[(16 + r) * 64 + lane];
    }
    lacc += mrg[2048 + lane];

    const float l = lacc + __shfl_xor(lacc, 32);
    if (!gr) {
        const float inv = 1.0f / l;
        unsigned short* dst = &AO[((size_t)(b * Tc + q)) * Dc + hd * HDc];
#pragma unroll
        for (int i = 0; i < 8; i++) {
            const int r = 2 * i;
            const int d = (r & 3) + 8 * (r >> 2) + 4 * h;
            *(unsigned*)&dst[d]      = pack2bf(acc0[r] * inv, acc0[r + 1] * inv);
            *(unsigned*)&dst[32 + d] = pack2bf(acc1[r] * inv, acc1[r + 1] * inv);
        }
    }
}

// ---------------------------------------------------------------------------
extern "C" void kernel_launch(void* const* d_in, const int* in_sizes, int n_in,
                              void* d_out, int out_size, void* d_ws, size_t ws_size,
                              hipStream_t stream)
{
    const float* x    = (const float*)d_in[0];
    const int*   ids  = (const int*)d_in[1];
    const float* Wqkv = (const float*)d_in[2];
    const float* bqkv = (const float*)d_in[3];
    const float* Wout = (const float*)d_in[4];
    const float* bout = (const float*)d_in[5];
    float* out = (float*)d_out;

    const size_t TEN = (size_t)Bc * Hc * Tc * HDc;   // 4,194,304 elements
    unsigned short* xb    = (unsigned short*)d_ws;            // 4.2M us
    unsigned short* wqkvb = xb + 4194304;                     // 3.1M us
    unsigned short* woutb = wqkvb + 3145728;                  // 1.0M us
    float2* ropeTab       = (float2*)(woutb + 1048576);       // 64K float2
    unsigned short* Qb    = (unsigned short*)(ropeTab + 65536);
    unsigned short* Kb    = Qb + TEN;
    unsigned short* Vtb   = Kb + TEN;
    unsigned short* AOb   = Vtb + TEN;                        // ~51 MB total

    // 0. fp32 -> bf16 conversions + RoPE table
    convert_bf16<<<8192, 256, 0, stream>>>(x, Wqkv, Wout, xb, wqkvb, woutb,
                                           ropeTab);
    // 1. QKV projection (MFMA) + fused RoPE -> bf16 Q/K [b,h,t,d], V^T [b,h,d,t]
    dim3 g1(3072 / 128, 4096 / 128);
    gemm_mfma<1><<<g1, 256, 0, stream>>>(xb, wqkvb, bqkv, nullptr,
                                         Qb, Kb, Vtb, ropeTab, 4096, 3072, 1024);
    // 2. attention (2-way key-split causal + global path) -> bf16 AO
    attn_fused<<<1056, 256, 0, stream>>>(Qb, Kb, Vtb, ids, AOb);
    // 3. output projection (MFMA, fp32 out)
    dim3 g4(1024 / 128, 4096 / 128);
    gemm_mfma<0><<<g4, 256, 0, stream>>>(AOb, woutb, bout, out,
                                         nullptr, nullptr, nullptr, nullptr,
                                         4096, 1024, 1024);
}

// Round 6
// 199.359 us; speedup vs baseline: 1.1794x; 1.0465x over previous
//
#include <hip/hip_runtime.h>
#include <math.h>

// Problem constants
#define Bc 2
#define Tc 2048
#define Dc 1024
#define Hc 16
#define HDc 64
// M = B*T = 4096, QKV N = 3072, K = 1024

typedef __attribute__((ext_vector_type(8))) short bf16x8;
typedef __attribute__((ext_vector_type(4))) float f32x4;
typedef __attribute__((ext_vector_type(16))) float f32x16;

__device__ __forceinline__ unsigned short f2bf(float f) {
    union { float f; unsigned int u; } v; v.f = f;
    unsigned int r = (v.u + 0x7FFFu + ((v.u >> 16) & 1u)) >> 16;   // RNE
    return (unsigned short)r;
}
// pack two fp32 -> bf16x2 dword (round-nearest, ties up): 3 VALU
__device__ __forceinline__ unsigned pack2bf(float a, float b) {
    unsigned au = __float_as_uint(a) + 0x8000u;
    unsigned bu = __float_as_uint(b) + 0x8000u;
    return __builtin_amdgcn_perm(bu, au, 0x07060302u);
}

// async global->LDS, 16 B per lane. LDS dest is WAVE-UNIFORM base + lane*16.
__device__ __forceinline__ void gload_lds16(const unsigned short* g,
                                            unsigned short* l) {
    __builtin_amdgcn_global_load_lds(
        (const __attribute__((address_space(1))) unsigned int*)g,
        (__attribute__((address_space(3))) unsigned int*)l,
        16, 0, 0);
}

// exp scale: 1/sqrt(64) * log2(e)  (fixed-max softmax: p = exp2(s*CEXP))
#define CEXP 0.1803368801111204f

// ---------------------------------------------------------------------------
// fp32 -> bf16 conversion for x, W_qkv, W_out + RoPE cos/sin table fill.
// ---------------------------------------------------------------------------
__global__ __launch_bounds__(256) void convert_bf16(
    const float* __restrict__ x, const float* __restrict__ wqkv,
    const float* __restrict__ wout,
    unsigned short* __restrict__ xb, unsigned short* __restrict__ wqkvb,
    unsigned short* __restrict__ woutb, float2* __restrict__ ropeTab)
{
    const int gid = blockIdx.x * 256 + threadIdx.x;
    // RoPE table: 2048 x 32 entries (cos, sin), angle = t * 10000^(-i/32)
    if (gid < Tc * 32) {
        const int t = gid >> 5, i = gid & 31;
        const float freq = exp2f((float)i * -0.4152410118609203f);
        const float ang = (float)t * freq;
        ropeTab[gid] = make_float2(cosf(ang), sinf(ang));
    }
    const int i = gid * 4;                        // 8,388,608 floats total
    const float* src; unsigned short* dst; int off;
    if (i < 4194304)      { src = x;    dst = xb;    off = i; }
    else if (i < 7340032) { src = wqkv; dst = wqkvb; off = i - 4194304; }
    else                  { src = wout; dst = woutb; off = i - 7340032; }
    float4 v = *(const float4*)&src[off];
    ushort4 o;
    o.x = f2bf(v.x); o.y = f2bf(v.y); o.z = f2bf(v.z); o.w = f2bf(v.w);
    *(ushort4*)&dst[off] = o;
}

// ---------------------------------------------------------------------------
// bf16 MFMA GEMM:  C[M,N] = A[M,K] @ W[N,K]^T + bias[N]
// BM=BN=128, BK=64, 256 thr = 4 waves (2x2), 64x64 per wave.
// Staging: async global_load_lds width=16 (linear LDS dest), with the global
// source oct PRE-SWIZZLED so LDS[r][o] = G[r][o ^ (r&7)] -> fragment reads
// (unchanged XOR addressing) stay 2-way-conflict-free (free per m136).
// MODE 0: fp32 C row-major + bias
// MODE 1: bf16 scatter with FUSED RoPE on Q,K -> [b,h,t,d]; V -> [b,h,d,t].
// ---------------------------------------------------------------------------
template <int MODE>
__global__ __launch_bounds__(256) void gemm_mfma(
    const unsigned short* __restrict__ A, const unsigned short* __restrict__ W,
    const float* __restrict__ bias, float* __restrict__ C,
    unsigned short* __restrict__ Qp, unsigned short* __restrict__ Kp,
    unsigned short* __restrict__ Vtp, const float2* __restrict__ ropeTab,
    int M, int N, int K)
{
    __shared__ unsigned short Apk[128 * 8 * 8];
    __shared__ unsigned short Bpk[128 * 8 * 8];

    const int tid = threadIdx.x;
    const int lane = tid & 63;
    const int wave = tid >> 6;
    const int quad = lane >> 4;
    const int c = lane & 15;
    const int wm = wave >> 1;
    const int wn = wave & 1;
    const int m0 = blockIdx.y * 128;
    const int n0 = blockIdx.x * 128;

    f32x4 acc[4][4];
#pragma unroll
    for (int mt = 0; mt < 4; mt++)
#pragma unroll
        for (int nt = 0; nt < 4; nt++) acc[mt][nt] = (f32x4){0.f, 0.f, 0.f, 0.f};

    // staging: wave-load of 1 KB covers 8 rows x 8 octs. lane -> (row, oct):
    // row_in_chunk = lane>>3, lds oct = lane&7 (fixed by HW linear layout).
    // source oct = (lane&7) ^ (r&7); since r&7 == lane>>3 for all chunks,
    // it's the lane-only constant below.
    const int lrow = lane >> 3;
    const int srcoct = (lane & 7) ^ lrow;

    for (int k0 = 0; k0 < K; k0 += 64) {
        __syncthreads();                       // prior tile's ds_reads done
#pragma unroll
        for (int i = 0; i < 4; i++) {
            const int r = wave * 32 + i * 8 + lrow;
            gload_lds16(&A[(size_t)(m0 + r) * K + k0 + srcoct * 8],
                        &Apk[(wave * 32 + i * 8) * 64]);
            gload_lds16(&W[(size_t)(n0 + r) * K + k0 + srcoct * 8],
                        &Bpk[(wave * 32 + i * 8) * 64]);
        }
        __syncthreads();                       // drains vmcnt(0): tile ready
#pragma unroll
        for (int ko = 0; ko < 2; ko++) {
            bf16x8 af[4], bf[4];
#pragma unroll
            for (int mt = 0; mt < 4; mt++) {
                const int m = wm * 64 + mt * 16 + c;
                af[mt] = *(const bf16x8*)&Apk[(m * 8 + ((ko * 4 + quad) ^ (m & 7))) * 8];
            }
#pragma unroll
            for (int nt = 0; nt < 4; nt++) {
                const int n = wn * 64 + nt * 16 + c;
                bf[nt] = *(const bf16x8*)&Bpk[(n * 8 + ((ko * 4 + quad) ^ (n & 7))) * 8];
            }
#pragma unroll
            for (int mt = 0; mt < 4; mt++)
#pragma unroll
                for (int nt = 0; nt < 4; nt++)
                    acc[mt][nt] = __builtin_amdgcn_mfma_f32_16x16x32_bf16(
                        af[mt], bf[nt], acc[mt][nt], 0, 0, 0);
        }
    }

    if (MODE == 0) {
#pragma unroll
        for (int mt = 0; mt < 4; mt++) {
            const int m = m0 + wm * 64 + mt * 16 + quad * 4;
#pragma unroll
            for (int nt = 0; nt < 4; nt++) {
                const int n = n0 + wn * 64 + nt * 16 + c;
                const float bv = bias[n];
#pragma unroll
                for (int reg = 0; reg < 4; reg++)
                    C[(size_t)(m + reg) * N + n] = acc[mt][nt][reg] + bv;
            }
        }
    } else {
        const int n_wave = n0 + wn * 64;          // 64-aligned -> one head/wave
        const int which = n_wave >> 10;           // 0=q,1=k,2=v (block-uniform)
        const int h = (n_wave >> 6) & 15;
        const int b = m0 >> 11;
        const int t_base = (m0 & 2047) + wm * 64;

        __syncthreads();   // all MFMA LDS reads done; reuse Apk/Bpk as staging
        // per-wave 8-KB staging region (wave-private; DS ops in-order per wave)
        unsigned short* stg = ((wave < 2) ? Apk : Bpk) + (wave & 1) * 4096;

        if (which < 2) {
            // ---- Q/K with fused RoPE: rotate -> LDS tile -> coalesced store
            unsigned short* dst = (which == 0) ? Qp : Kp;
#pragma unroll
            for (int mt = 0; mt < 4; mt++) {
#pragma unroll
                for (int nt = 0; nt < 2; nt++) {
                    const int i1 = nt * 16 + c;            // rotary index 0..31
                    const float bv1 = bias[n_wave + i1];
                    const float bv2 = bias[n_wave + 32 + i1];
#pragma unroll
                    for (int reg = 0; reg < 4; reg++) {
                        const int row = mt * 16 + quad * 4 + reg;
                        const float2 cs = ropeTab[(t_base + row) * 32 + i1];
                        const float x1 = acc[mt][nt][reg] + bv1;
                        const float x2 = acc[mt][nt + 2][reg] + bv2;
                        const int col2 = 32 + i1;
                        stg[(row * 8 + ((i1 >> 3) ^ (row & 7))) * 8 + (i1 & 7)] =
                            f2bf(x1 * cs.x - x2 * cs.y);
                        stg[(row * 8 + ((col2 >> 3) ^ (row & 7))) * 8 + (col2 & 7)] =
                            f2bf(x1 * cs.y + x2 * cs.x);
                    }
                }
            }
            // tile [t_base..t_base+63][0..63] is 8 KB CONTIGUOUS in Q/K
            const size_t obase = ((size_t)(b * Hc + h) * Tc + t_base) * HDc;
            const int oct = lane & 7;
#pragma unroll
            for (int k = 0; k < 8; k++) {
                const int f = lane * 8 + k * 512;       // flat ushort offset
                const int row = f >> 6;
                bf16x8 vv = *(const bf16x8*)&stg[(row * 8 + (oct ^ (row & 7))) * 8];
                *(bf16x8*)&dst[obase + f] = vv;         // 64 lanes x 16 B = 1 KB
            }
        } else {
            // ---- V: stage transposed tile [d][t], store full 128-B d-rows
#pragma unroll
            for (int mt = 0; mt < 4; mt++) {
#pragma unroll
                for (int nt = 0; nt < 4; nt++) {
                    const int d = nt * 16 + c;
                    const float bv = bias[n_wave + d];
#pragma unroll
                    for (int reg = 0; reg < 4; reg++) {
                        const int r = mt * 16 + quad * 4 + reg;   // t within tile
                        stg[(d * 8 + ((r >> 3) ^ (d & 7))) * 8 + (r & 7)] =
                            f2bf(acc[mt][nt][reg] + bv);
                    }
                }
            }
            const size_t vbase = (size_t)(b * Hc + h) * HDc * Tc;
            const int oct = lane & 7;                   // t-chunk
#pragma unroll
            for (int k = 0; k < 8; k++) {
                const int d = (lane >> 3) + k * 8;
                bf16x8 vv = *(const bf16x8*)&stg[(d * 8 + (oct ^ (d & 7))) * 8];
                // 8 lanes cover one full 128-B line per d-row
                *(bf16x8*)&Vtp[vbase + (size_t)d * Tc + t_base + oct * 8] = vv;
            }
        }
    }
}

// ---------------------------------------------------------------------------
// Fused attention. Grid = 1056 blocks:
//   blk 0..31    : global-query rows (full-T, one block per bh).
//   blk 32..1055 : causal, 2-way KEY-SPLIT + SINGLE-BARRIER DOUBLE-BUFFER:
//     per 64-key step s: barrier -> issue stage(s+1) -> compute(s).
//     Next step's gload_lds loads fly under the WHOLE current compute
//     (~1200cy >> L2 latency); the per-wave vmcnt(0) drain at the barrier
//     comes AFTER compute => ~zero stall. One barrier per 64 keys (was 2).
//     Tiles are 32 keys so the double buffer fits 33 KB LDS:
//       step buffer = K0[32x64] + K1 + V0[64x32] + V1 = 16 KB, x2 = 32 KB.
//     Waves {0,1} compute even 32-tiles (grp 0), {2,3} odd (grp 1);
//     staging: wave0->K0, wave1->K1, wave2->V0, wave3->V1 (4 gloads each).
//     Hazards: stage(s+1) overwrites buf consumed at step s-1 (pre-barrier
//     done); __syncthreads drains each wave's own gloads => tile complete.
//     (256,4) kept: R2/R5 A/B showed it worth ~10us even with spills; with
//     32-key tiles peak live state is ~88 VGPR so forced allocation spills
//     far less than R2's.
// ---------------------------------------------------------------------------
__global__ __launch_bounds__(256, 4) void attn_fused(
    const unsigned short* __restrict__ Q, const unsigned short* __restrict__ K,
    const unsigned short* __restrict__ Vt, const int* __restrict__ ids,
    unsigned short* __restrict__ AO)
{
    __shared__ __align__(16) float smem[8448];   // 33792 B, overlaid per path

    const int tid = threadIdx.x;
    const int lane = tid & 63;
    const int wave = tid >> 6;
    const int c32 = lane & 31;
    const int h = lane >> 5;
    const int blk = blockIdx.x;

    if (blk < 32) {
        // ================= global-query rows =================
        int* s_list = (int*)smem;                 // 64
        int* s_cnt = (int*)smem + 64;
        float* s_accm = smem + 128;               // [4][64][32]
        float* s_lm = s_accm + 8192;              // [4][32]

        const int bh = blk;
        const int b = bh >> 4;
        const int hd = bh & 15;
        const size_t qkbase = (size_t)bh * Tc * HDc;

        if (tid == 0) *s_cnt = 0;
        __syncthreads();
        for (int i = tid; i < Tc; i += 256) {
            int id = ids[b * Tc + i];
            if ((unsigned)(id - 2) <= 5u) {
                int p = atomicAdd(s_cnt, 1);
                if (p < 64) s_list[p] = i;
            }
        }
        __syncthreads();
        const int cnt = min(*s_cnt, 64);

        for (int pass = 0; pass * 32 < cnt; pass++) {
            const int slot = pass * 32 + c32;
            const int row = (slot < cnt) ? s_list[slot] : s_list[0];

            bf16x8 qf[4];
#pragma unroll
            for (int ko = 0; ko < 4; ko++)
                qf[ko] = *(const bf16x8*)&Q[qkbase + (size_t)row * HDc + ko * 16 + h * 8];

            f32x16 acc0 = {}, acc1 = {};
            float lacc = 0.0f;

            for (int it = wave; it < Tc / 64; it += 4) {
                const int t0 = it * 64;
                f32x16 s0 = {}, s1 = {};
#pragma unroll
                for (int ko = 0; ko < 4; ko++) {
                    const int koff = ko * 16 + h * 8;
                    bf16x8 kf0 = *(const bf16x8*)&K[qkbase + (size_t)(t0 + c32) * HDc + koff];
                    bf16x8 kf1 = *(const bf16x8*)&K[qkbase + (size_t)(t0 + 32 + c32) * HDc + koff];
                    s0 = __builtin_amdgcn_mfma_f32_32x32x16_bf16(kf0, qf[ko], s0, 0, 0, 0);
                    s1 = __builtin_amdgcn_mfma_f32_32x32x16_bf16(kf1, qf[ko], s1, 0, 0, 0);
                }
                float v[32];
#pragma unroll
                for (int r = 0; r < 16; r++) { v[r] = s0[r]; v[16 + r] = s1[r]; }
#pragma unroll
                for (int i = 0; i < 32; i++) v[i] = exp2f(v[i] * CEXP);
                unsigned pk[16];
#pragma unroll
                for (int i = 0; i < 16; i++) pk[i] = pack2bf(v[2 * i], v[2 * i + 1]);
#pragma unroll
                for (int st = 1; st < 32; st <<= 1)
#pragma unroll
                    for (int i = 0; i < 32; i += 2 * st) v[i] += v[i + st];
                lacc += v[0];
#pragma unroll
                for (int ko = 0; ko < 4; ko++) {
                    const int a = (ko >> 1) * 8 + (ko & 1) * 4;
                    unsigned keep0 = h ? pk[a + 2] : pk[a + 0];
                    unsigned keep1 = h ? pk[a + 3] : pk[a + 1];
                    unsigned send0 = h ? pk[a + 0] : pk[a + 2];
                    unsigned send1 = h ? pk[a + 1] : pk[a + 3];
                    unsigned recv0 = (unsigned)__shfl_xor((int)send0, 32);
                    unsigned recv1 = (unsigned)__shfl_xor((int)send1, 32);
                    union { bf16x8 v8; unsigned u[4]; } pf;
                    pf.u[0] = h ? recv0 : keep0;
                    pf.u[1] = h ? recv1 : keep1;
                    pf.u[2] = h ? keep0 : recv0;
                    pf.u[3] = h ? keep1 : recv1;
                    const int oct = ko * 2 + h;
                    bf16x8 vf0 = *(const bf16x8*)&Vt[qkbase + (size_t)c32 * Tc + t0 + oct * 8];
                    bf16x8 vf1 = *(const bf16x8*)&Vt[qkbase + (size_t)(32 + c32) * Tc + t0 + oct * 8];
                    acc0 = __builtin_amdgcn_mfma_f32_32x32x16_bf16(vf0, pf.v8, acc0, 0, 0, 0);
                    acc1 = __builtin_amdgcn_mfma_f32_32x32x16_bf16(vf1, pf.v8, acc1, 0, 0, 0);
                }
            }

            const float lfull = lacc + __shfl_xor(lacc, 32);
            if (h == 0) s_lm[wave * 32 + c32] = lfull;
#pragma unroll
            for (int r = 0; r < 16; r++) {
                const int d = (r & 3) + 8 * (r >> 2) + 4 * h;
                s_accm[(wave * 64 + d) * 32 + c32] = acc0[r];
                s_accm[(wave * 64 + 32 + d) * 32 + c32] = acc1[r];
            }
            __syncthreads();
            for (int i = tid; i < 2048; i += 256) {
                const int sl = i >> 6, d = i & 63;
                if (pass * 32 + sl < cnt) {
                    const float o = s_accm[(0 * 64 + d) * 32 + sl] + s_accm[(1 * 64 + d) * 32 + sl] +
                                    s_accm[(2 * 64 + d) * 32 + sl] + s_accm[(3 * 64 + d) * 32 + sl];
                    const float lt = s_lm[sl] + s_lm[32 + sl] + s_lm[64 + sl] + s_lm[96 + sl];
                    const int qrow = s_list[pass * 32 + sl];
                    AO[((size_t)(b * Tc + qrow)) * Dc + hd * HDc + d] = f2bf(o / lt);
                }
            }
            __syncthreads();
        }
        return;
    }

    // ====== causal path: key-split, single-barrier double-buffered steps =====
    unsigned short* KV = (unsigned short*)smem;    // 2 step-buffers x 8192 us

    const int idx = blk - 32;                      // 0..1023
    const int bh = (idx & 7) + 8 * ((idx >> 3) & 3);   // 4 bh per XCD
    const int b = bh >> 4;
    const int hd = bh & 15;
    // weight index -> j so stride-8 samples {w, w+8, w+16, w+24} (one CU's 4
    // resident blocks) give j = {u, 31-u, 8+u, 23-u}: nS sum == 66 const.
    const int w = idx >> 5;                        // 0..31
    const int u = w & 7, tq = w >> 3;
    const int j = (tq == 0) ? u : (tq == 1) ? 31 - u : (tq == 2) ? 8 + u : 23 - u;
    const int qb0 = j * 64;
    const int nS = j + 1;                          // 64-key steps in [0, qb0+64)
    const int grp = wave >> 1;                     // 0: even 32-tile, 1: odd
    const int wq0 = qb0 + (wave & 1) * 32;         // wave's 32 q rows
    const size_t qkbase = (size_t)bh * Tc * HDc;
    const int q = wq0 + c32;

    // Q B-fragments (whole kernel): B[k=hd=ko*16+h*8+j][n=q=c32]
    bf16x8 qf[4];
#pragma unroll
    for (int ko = 0; ko < 4; ko++)
        qf[ko] = *(const bf16x8*)&Q[qkbase + (size_t)q * HDc + ko * 16 + h * 8];

    const int myid = ids[b * Tc + q];
    const bool gr = ((unsigned)(myid - 2) <= 5u);  // global row: store suppressed

    f32x16 acc0 = {}, acc1 = {};
    float lacc = 0.0f;

    // staging source pre-swizzles (linear LDS dest, swizzled global source)
    const int srcK = (lane & 7) ^ (lane >> 3);         // K rows: 64-elem, 8 octs
    const int srcV = (lane & 3) ^ ((lane >> 2) & 3);   // V rows: 32-elem, 4 octs

    // one step-buffer: K0[32x64] K1[32x64] V0[64x32] V1[64x32] = 8192 ushorts
    auto stageStep = [&](int s, int sbuf) {
        unsigned short* B = KV + sbuf * 8192;
        const int t0 = s * 64;
        if (wave < 2) {
            unsigned short* Kb = B + wave * 2048;      // wave0->K0, wave1->K1
            const int tk = t0 + wave * 32;
#pragma unroll
            for (int c = 0; c < 4; c++) {
                const int row = c * 8 + (lane >> 3);   // 0..31
                gload_lds16(&K[qkbase + (size_t)(tk + row) * HDc + srcK * 8],
                            &Kb[c * 512]);
            }
        } else {
            unsigned short* Vb = B + 4096 + (wave & 1) * 2048;  // V0 / V1
            const int tv = t0 + (wave & 1) * 32;
#pragma unroll
            for (int c = 0; c < 4; c++) {
                const int d = c * 16 + (lane >> 2);    // 0..63
                gload_lds16(&Vt[qkbase + (size_t)d * Tc + tv + srcV * 8],
                            &Vb[c * 512]);
            }
        }
    };

    auto computeT32 = [&](int t0, const unsigned short* Kb, const unsigned short* Vb) {
        // --- scores S^T[key 0..31][q]: contraction 64 = 4 MFMAs
        f32x16 s0 = {};
#pragma unroll
        for (int ko = 0; ko < 4; ko++) {
            const int oct = ko * 2 + h;
            bf16x8 kf = *(const bf16x8*)&Kb[(c32 * 8 + (oct ^ (c32 & 7))) * 8];
            s0 = __builtin_amdgcn_mfma_f32_32x32x16_bf16(kf, qf[ko], s0, 0, 0, 0);
        }

        // --- fixed-max softmax: p = exp2(s*CEXP)
        float v[16];
#pragma unroll
        for (int r = 0; r < 16; r++) v[r] = exp2f(s0[r] * CEXP);

        if (t0 + 31 > wq0) {                       // wave-uniform (diag tile)
            const int thr = wq0 + c32 - t0 - 4 * h;
#pragma unroll
            for (int r = 0; r < 16; r++) {
                const int ckr = (r & 3) + 8 * (r >> 2);
                v[r] = (ckr <= thr) ? v[r] : 0.0f;
            }
        }

        unsigned pk[8];
#pragma unroll
        for (int i = 0; i < 8; i++) pk[i] = pack2bf(v[2 * i], v[2 * i + 1]);

        // l accumulation: depth-4 pairwise tree, no cross-lane op
#pragma unroll
        for (int st = 1; st < 16; st <<= 1)
#pragma unroll
            for (int i = 0; i < 16; i += 2 * st) v[i] += v[i + st];
        lacc += v[0];

        // --- PV: O^T += V^T x P^T (2 key-slices of 16)
#pragma unroll
        for (int ks = 0; ks < 2; ks++) {
            const int a = ks * 4;
            unsigned keep0 = h ? pk[a + 2] : pk[a + 0];
            unsigned keep1 = h ? pk[a + 3] : pk[a + 1];
            unsigned send0 = h ? pk[a + 0] : pk[a + 2];
            unsigned send1 = h ? pk[a + 1] : pk[a + 3];
            unsigned recv0 = (unsigned)__shfl_xor((int)send0, 32);
            unsigned recv1 = (unsigned)__shfl_xor((int)send1, 32);
            union { bf16x8 v8; unsigned u[4]; } pf;
            pf.u[0] = h ? recv0 : keep0;
            pf.u[1] = h ? recv1 : keep1;
            pf.u[2] = h ? keep0 : recv0;
            pf.u[3] = h ? keep1 : recv1;
            const int oct = ks * 2 + h;
            const int d0 = c32, d1 = 32 + c32;
            bf16x8 vf0 = *(const bf16x8*)&Vb[(d0 * 4 + (oct ^ (d0 & 3))) * 8];
            bf16x8 vf1 = *(const bf16x8*)&Vb[(d1 * 4 + (oct ^ (d1 & 3))) * 8];
            acc0 = __builtin_amdgcn_mfma_f32_32x32x16_bf16(vf0, pf.v8, acc0, 0, 0, 0);
            acc1 = __builtin_amdgcn_mfma_f32_32x32x16_bf16(vf1, pf.v8, acc1, 0, 0, 0);
        }
    };

    // single-barrier double-buffered step loop:
    //   barrier (step s ready: every wave drained its own stage gloads)
    //   -> issue stage(s+1) (flies under compute) -> compute(s)
    stageStep(0, 0);
    for (int s = 0; s < nS; s++) {
        __syncthreads();
        if (s + 1 < nS) stageStep(s + 1, (s + 1) & 1);
        const int t0 = (2 * s + grp) * 32;
        if (t0 <= wq0 + 31) {                      // wave-level causal skip
            const unsigned short* B = KV + (s & 1) * 8192;
            computeT32(t0, B + grp * 2048, B + 4096 + grp * 2048);
        }
    }

    // --- merge key-split partials: wave 2->0, 3->1 via LDS ([r][lane]: no
    // bank conflicts), then h-halves of l, then store.
    __syncthreads();
    float* mrg = smem + (wave & 1) * 2176;         // 2 pairs x 2176 f32
    if (wave >= 2) {
#pragma unroll
        for (int r = 0; r < 16; r++) {
            mrg[r * 64 + lane] = acc0[r];
            mrg[(16 + r) * 64 + lane] = acc1[r];
        }
        mrg[2048 + lane] = lacc;
    }
    __syncthreads();
    if (wave >= 2) return;
#pragma unroll
    for (int r = 0; r < 16; r++) {
        acc0[r] += mrg[r * 64 + lane];
        acc1[r] += mrg[(16 + r) * 64 + lane];
    }
    lacc += mrg[2048 + lane];

    const float l = lacc + __shfl_xor(lacc, 32);
    if (!gr) {
        const float inv = 1.0f / l;
        unsigned short* dst = &AO[((size_t)(b * Tc + q)) * Dc + hd * HDc];
#pragma unroll
        for (int i = 0; i < 8; i++) {
            const int r = 2 * i;
            const int d = (r & 3) + 8 * (r >> 2) + 4 * h;
            *(unsigned*)&dst[d]      = pack2bf(acc0[r] * inv, acc0[r + 1] * inv);
            *(unsigned*)&dst[32 + d] = pack2bf(acc1[r] * inv, acc1[r + 1] * inv);
        }
    }
}

// ---------------------------------------------------------------------------
extern "C" void kernel_launch(void* const* d_in, const int* in_sizes, int n_in,
                              void* d_out, int out_size, void* d_ws, size_t ws_size,
                              hipStream_t stream)
{
    const float* x    = (const float*)d_in[0];
    const int*   ids  = (const int*)d_in[1];
    const float* Wqkv = (const float*)d_in[2];
    const float* bqkv = (const float*)d_in[3];
    const float* Wout = (const float*)d_in[4];
    const float* bout = (const float*)d_in[5];
    float* out = (float*)d_out;

    const size_t TEN = (size_t)Bc * Hc * Tc * HDc;   // 4,194,304 elements
    unsigned short* xb    = (unsigned short*)d_ws;            // 4.2M us
    unsigned short* wqkvb = xb + 4194304;                     // 3.1M us
    unsigned short* woutb = wqkvb + 3145728;                  // 1.0M us
    float2* ropeTab       = (float2*)(woutb + 1048576);       // 64K float2
    unsigned short* Qb    = (unsigned short*)(ropeTab + 65536);
    unsigned short* Kb    = Qb + TEN;
    unsigned short* Vtb   = Kb + TEN;
    unsigned short* AOb   = Vtb + TEN;                        // ~51 MB total

    // 0. fp32 -> bf16 conversions + RoPE table
    convert_bf16<<<8192, 256, 0, stream>>>(x, Wqkv, Wout, xb, wqkvb, woutb,
                                           ropeTab);
    // 1. QKV projection (MFMA) + fused RoPE -> bf16 Q/K [b,h,t,d], V^T [b,h,d,t]
    dim3 g1(3072 / 128, 4096 / 128);
    gemm_mfma<1><<<g1, 256, 0, stream>>>(xb, wqkvb, bqkv, nullptr,
                                         Qb, Kb, Vtb, ropeTab, 4096, 3072, 1024);
    // 2. attention (single-barrier double-buffered causal + global path)
    attn_fused<<<1056, 256, 0, stream>>>(Qb, Kb, Vtb, ids, AOb);
    // 3. output projection (MFMA, fp32 out)
    dim3 g4(1024 / 128, 4096 / 128);
    gemm_mfma<0><<<g4, 256, 0, stream>>>(AOb, woutb, bout, out,
                                         nullptr, nullptr, nullptr, nullptr,
                                         4096, 1024, 1024);
}

// Round 7
// 193.466 us; speedup vs baseline: 1.2154x; 1.0305x over previous
//
#include <hip/hip_runtime.h>
#include <math.h>

// Problem constants
#define Bc 2
#define Tc 2048
#define Dc 1024
#define Hc 16
#define HDc 64
// M = B*T = 4096, QKV N = 3072, K = 1024

typedef __attribute__((ext_vector_type(8))) short bf16x8;
typedef __attribute__((ext_vector_type(4))) float f32x4;
typedef __attribute__((ext_vector_type(16))) float f32x16;

__device__ __forceinline__ unsigned short f2bf(float f) {
    union { float f; unsigned int u; } v; v.f = f;
    unsigned int r = (v.u + 0x7FFFu + ((v.u >> 16) & 1u)) >> 16;   // RNE
    return (unsigned short)r;
}
// pack two fp32 -> bf16x2 dword (round-nearest, ties up): 3 VALU
__device__ __forceinline__ unsigned pack2bf(float a, float b) {
    unsigned au = __float_as_uint(a) + 0x8000u;
    unsigned bu = __float_as_uint(b) + 0x8000u;
    return __builtin_amdgcn_perm(bu, au, 0x07060302u);
}

// async global->LDS, 16 B per lane. LDS dest is WAVE-UNIFORM base + lane*16.
__device__ __forceinline__ void gload_lds16(const unsigned short* g,
                                            unsigned short* l) {
    __builtin_amdgcn_global_load_lds(
        (const __attribute__((address_space(1))) unsigned int*)g,
        (__attribute__((address_space(3))) unsigned int*)l,
        16, 0, 0);
}

// exp scale: 1/sqrt(64) * log2(e)  (fixed-max softmax: p = exp2(s*CEXP))
#define CEXP 0.1803368801111204f

// ---------------------------------------------------------------------------
// fp32 -> bf16 conversion for x, W_qkv, W_out + RoPE cos/sin table fill.
// Grid-stride (G11): 2048 blocks x 4 iterations of float4 (was 8192 one-shot;
// measured 3.7 TB/s effective -> target ~6).
// ---------------------------------------------------------------------------
__global__ __launch_bounds__(256) void convert_bf16(
    const float* __restrict__ x, const float* __restrict__ wqkv,
    const float* __restrict__ wout,
    unsigned short* __restrict__ xb, unsigned short* __restrict__ wqkvb,
    unsigned short* __restrict__ woutb, float2* __restrict__ ropeTab)
{
    const int gid = blockIdx.x * 256 + threadIdx.x;      // 0..524287
    // RoPE table: 2048 x 32 entries (cos, sin), angle = t * 10000^(-i/32)
    if (gid < Tc * 32) {
        const int t = gid >> 5, i = gid & 31;
        const float freq = exp2f((float)i * -0.4152410118609203f);
        const float ang = (float)t * freq;
        ropeTab[gid] = make_float2(cosf(ang), sinf(ang));
    }
#pragma unroll
    for (int it = 0; it < 4; it++) {
        const int i = (it * 524288 + gid) * 4;           // 8,388,608 floats
        const float* src; unsigned short* dst; int off;
        if (i < 4194304)      { src = x;    dst = xb;    off = i; }
        else if (i < 7340032) { src = wqkv; dst = wqkvb; off = i - 4194304; }
        else                  { src = wout; dst = woutb; off = i - 7340032; }
        float4 v = *(const float4*)&src[off];
        ushort4 o;
        o.x = f2bf(v.x); o.y = f2bf(v.y); o.z = f2bf(v.z); o.w = f2bf(v.w);
        *(ushort4*)&dst[off] = o;
    }
}

// ---------------------------------------------------------------------------
// bf16 MFMA GEMM:  C[M,N] = A[M,K] @ W[N,K]^T + bias[N]
// Block tile (MT*32) x (NT*32), BK=64, 256 thr = 4 waves (2x2),
// per-wave tile (MT*16) x (NT*16) frags of 16x16x32.
//   <1,4,4>: 128x128 QKV + fused RoPE epilogue (Q/K [b,h,t,d]; V^T [b,h,d,t])
//   <0,2,2>: 64x64 out-proj (fp32 C + bias) — grid 1024 blocks = 4/CU
//            (128x128 gave 256 blocks = 1/CU, 8% occupancy, 26us)
// Staging: async global_load_lds width=16 (linear LDS dest), global source
// oct PRE-SWIZZLED so LDS[r][o] = G[r][o ^ (r&7)] -> fragment reads stay
// 2-way-conflict-free.
// XCD-aware bijective remap (T1): per XCD a contiguous band of n-cols,
// traversed m-major -> A panel reused cpx x back-to-back, W band L2-resident.
// ---------------------------------------------------------------------------
template <int MODE, int MT, int NT>
__global__ __launch_bounds__(256) void gemm_mfma(
    const unsigned short* __restrict__ A, const unsigned short* __restrict__ W,
    const float* __restrict__ bias, float* __restrict__ C,
    unsigned short* __restrict__ Qp, unsigned short* __restrict__ Kp,
    unsigned short* __restrict__ Vtp, const float2* __restrict__ ropeTab,
    int M, int N, int K)
{
    __shared__ unsigned short Apk[MT * 32 * 64];
    __shared__ unsigned short Bpk[NT * 32 * 64];

    const int tid = threadIdx.x;
    const int lane = tid & 63;
    const int wave = tid >> 6;
    const int quad = lane >> 4;
    const int c = lane & 15;
    const int wm = wave >> 1;
    const int wn = wave & 1;

    // XCD-aware remap: flat%8 = XCD (HW round-robin); within an XCD, walk
    // m-major across cpx n-cols. Bijective since grid % 8 == 0.
    const int flat = blockIdx.y * gridDim.x + blockIdx.x;
    const int cpx = gridDim.x >> 3;                  // n-cols per XCD
    const int xcd = flat & 7;
    const int idxq = flat >> 3;
    const int bx = xcd * cpx + (idxq % cpx);
    const int by = idxq / cpx;
    const int m0 = by * (MT * 32);
    const int n0 = bx * (NT * 32);

    f32x4 acc[MT][NT];
#pragma unroll
    for (int mt = 0; mt < MT; mt++)
#pragma unroll
        for (int nt = 0; nt < NT; nt++) acc[mt][nt] = (f32x4){0.f, 0.f, 0.f, 0.f};

    // staging: wave-load of 1 KB covers 8 rows x 8 octs. lane -> (row, oct):
    // row_in_chunk = lane>>3, lds oct = lane&7 (fixed by HW linear layout).
    // source oct = (lane&7) ^ (r&7); r&7 == lane>>3 for all 8-aligned chunks.
    const int lrow = lane >> 3;
    const int srcoct = (lane & 7) ^ lrow;

    for (int k0 = 0; k0 < K; k0 += 64) {
        __syncthreads();                       // prior tile's ds_reads done
#pragma unroll
        for (int i = 0; i < MT; i++) {
            const int r = wave * (MT * 8) + i * 8 + lrow;
            gload_lds16(&A[(size_t)(m0 + r) * K + k0 + srcoct * 8],
                        &Apk[(wave * MT * 8 + i * 8) * 64]);
        }
#pragma unroll
        for (int i = 0; i < NT; i++) {
            const int r = wave * (NT * 8) + i * 8 + lrow;
            gload_lds16(&W[(size_t)(n0 + r) * K + k0 + srcoct * 8],
                        &Bpk[(wave * NT * 8 + i * 8) * 64]);
        }
        __syncthreads();                       // drains vmcnt(0): tile ready
#pragma unroll
        for (int ko = 0; ko < 2; ko++) {
            bf16x8 af[MT], bf[NT];
#pragma unroll
            for (int mt = 0; mt < MT; mt++) {
                const int m = wm * (MT * 16) + mt * 16 + c;
                af[mt] = *(const bf16x8*)&Apk[(m * 8 + ((ko * 4 + quad) ^ (m & 7))) * 8];
            }
#pragma unroll
            for (int nt = 0; nt < NT; nt++) {
                const int n = wn * (NT * 16) + nt * 16 + c;
                bf[nt] = *(const bf16x8*)&Bpk[(n * 8 + ((ko * 4 + quad) ^ (n & 7))) * 8];
            }
#pragma unroll
            for (int mt = 0; mt < MT; mt++)
#pragma unroll
                for (int nt = 0; nt < NT; nt++)
                    acc[mt][nt] = __builtin_amdgcn_mfma_f32_16x16x32_bf16(
                        af[mt], bf[nt], acc[mt][nt], 0, 0, 0);
        }
    }

    if (MODE == 0) {
#pragma unroll
        for (int mt = 0; mt < MT; mt++) {
            const int m = m0 + wm * (MT * 16) + mt * 16 + quad * 4;
#pragma unroll
            for (int nt = 0; nt < NT; nt++) {
                const int n = n0 + wn * (NT * 16) + nt * 16 + c;
                const float bv = bias[n];
#pragma unroll
                for (int reg = 0; reg < 4; reg++)
                    C[(size_t)(m + reg) * N + n] = acc[mt][nt][reg] + bv;
            }
        }
    } else {
        const int n_wave = n0 + wn * 64;          // 64-aligned -> one head/wave
        const int which = n_wave >> 10;           // 0=q,1=k,2=v (block-uniform)
        const int h = (n_wave >> 6) & 15;
        const int b = m0 >> 11;
        const int t_base = (m0 & 2047) + wm * 64;

        __syncthreads();   // all MFMA LDS reads done; reuse Apk/Bpk as staging
        // per-wave 8-KB staging region (wave-private; DS ops in-order per wave)
        unsigned short* stg = ((wave < 2) ? Apk : Bpk) + (wave & 1) * 4096;

        if (which < 2) {
            // ---- Q/K with fused RoPE: rotate -> LDS tile -> coalesced store
            unsigned short* dst = (which == 0) ? Qp : Kp;
#pragma unroll
            for (int mt = 0; mt < 4; mt++) {
#pragma unroll
                for (int nt = 0; nt < 2; nt++) {
                    const int i1 = nt * 16 + c;            // rotary index 0..31
                    const float bv1 = bias[n_wave + i1];
                    const float bv2 = bias[n_wave + 32 + i1];
#pragma unroll
                    for (int reg = 0; reg < 4; reg++) {
                        const int row = mt * 16 + quad * 4 + reg;
                        const float2 cs = ropeTab[(t_base + row) * 32 + i1];
                        const float x1 = acc[mt][nt][reg] + bv1;
                        const float x2 = acc[mt][nt + 2][reg] + bv2;
                        const int col2 = 32 + i1;
                        stg[(row * 8 + ((i1 >> 3) ^ (row & 7))) * 8 + (i1 & 7)] =
                            f2bf(x1 * cs.x - x2 * cs.y);
                        stg[(row * 8 + ((col2 >> 3) ^ (row & 7))) * 8 + (col2 & 7)] =
                            f2bf(x1 * cs.y + x2 * cs.x);
                    }
                }
            }
            // tile [t_base..t_base+63][0..63] is 8 KB CONTIGUOUS in Q/K
            const size_t obase = ((size_t)(b * Hc + h) * Tc + t_base) * HDc;
            const int oct = lane & 7;
#pragma unroll
            for (int k = 0; k < 8; k++) {
                const int f = lane * 8 + k * 512;       // flat ushort offset
                const int row = f >> 6;
                bf16x8 vv = *(const bf16x8*)&stg[(row * 8 + (oct ^ (row & 7))) * 8];
                *(bf16x8*)&dst[obase + f] = vv;         // 64 lanes x 16 B = 1 KB
            }
        } else {
            // ---- V: stage transposed tile [d][t], store full 128-B d-rows
#pragma unroll
            for (int mt = 0; mt < 4; mt++) {
#pragma unroll
                for (int nt = 0; nt < 4; nt++) {
                    const int d = nt * 16 + c;
                    const float bv = bias[n_wave + d];
#pragma unroll
                    for (int reg = 0; reg < 4; reg++) {
                        const int r = mt * 16 + quad * 4 + reg;   // t within tile
                        stg[(d * 8 + ((r >> 3) ^ (d & 7))) * 8 + (r & 7)] =
                            f2bf(acc[mt][nt][reg] + bv);
                    }
                }
            }
            const size_t vbase = (size_t)(b * Hc + h) * HDc * Tc;
            const int oct = lane & 7;                   // t-chunk
#pragma unroll
            for (int k = 0; k < 8; k++) {
                const int d = (lane >> 3) + k * 8;
                bf16x8 vv = *(const bf16x8*)&stg[(d * 8 + (oct ^ (d & 7))) * 8];
                // 8 lanes cover one full 128-B line per d-row
                *(bf16x8*)&Vtp[vbase + (size_t)d * Tc + t_base + oct * 8] = vv;
            }
        }
    }
}

// ---------------------------------------------------------------------------
// Fused attention (exact R2 structure — best measured 52.8us, absmax 2^-7).
// Grid = 1056 blocks:
//   blk 0..31    : global-query rows (full-T, one block per bh).
//   blk 32..1055 : causal, 2-way KEY-SPLIT (fixed-max softmax => O,l partials
//     are linear and just add):
//       each block owns 64 q rows of one bh; waves {0,1} compute EVEN 64-key
//       tiles, waves {2,3} ODD tiles (same q rows); partials merged via LDS.
//     Staging: global_load_lds width=16 into a single-buffered tile PAIR
//     (Ke/Ve even, Ko/Vo odd; 32 KB), 2 barriers per pair — occupancy-first:
//     __launch_bounds__(256,4) => 4 blocks/CU resident (R2/R5 A/B: worth
//     ~10us even though it forces VGPR=64 + spills).
// ---------------------------------------------------------------------------
__global__ __launch_bounds__(256, 4) void attn_fused(
    const unsigned short* __restrict__ Q, const unsigned short* __restrict__ K,
    const unsigned short* __restrict__ Vt, const int* __restrict__ ids,
    unsigned short* __restrict__ AO)
{
    __shared__ __align__(16) float smem[8448];   // 33792 B, overlaid per path

    const int tid = threadIdx.x;
    const int lane = tid & 63;
    const int wave = tid >> 6;
    const int c32 = lane & 31;
    const int h = lane >> 5;
    const int blk = blockIdx.x;

    if (blk < 32) {
        // ================= global-query rows =================
        int* s_list = (int*)smem;                 // 64
        int* s_cnt = (int*)smem + 64;
        float* s_accm = smem + 128;               // [4][64][32]
        float* s_lm = s_accm + 8192;              // [4][32]

        const int bh = blk;
        const int b = bh >> 4;
        const int hd = bh & 15;
        const size_t qkbase = (size_t)bh * Tc * HDc;

        if (tid == 0) *s_cnt = 0;
        __syncthreads();
        for (int i = tid; i < Tc; i += 256) {
            int id = ids[b * Tc + i];
            if ((unsigned)(id - 2) <= 5u) {
                int p = atomicAdd(s_cnt, 1);
                if (p < 64) s_list[p] = i;
            }
        }
        __syncthreads();
        const int cnt = min(*s_cnt, 64);

        for (int pass = 0; pass * 32 < cnt; pass++) {
            const int slot = pass * 32 + c32;
            const int row = (slot < cnt) ? s_list[slot] : s_list[0];

            bf16x8 qf[4];
#pragma unroll
            for (int ko = 0; ko < 4; ko++)
                qf[ko] = *(const bf16x8*)&Q[qkbase + (size_t)row * HDc + ko * 16 + h * 8];

            f32x16 acc0 = {}, acc1 = {};
            float lacc = 0.0f;

            for (int it = wave; it < Tc / 64; it += 4) {
                const int t0 = it * 64;
                f32x16 s0 = {}, s1 = {};
#pragma unroll
                for (int ko = 0; ko < 4; ko++) {
                    const int koff = ko * 16 + h * 8;
                    bf16x8 kf0 = *(const bf16x8*)&K[qkbase + (size_t)(t0 + c32) * HDc + koff];
                    bf16x8 kf1 = *(const bf16x8*)&K[qkbase + (size_t)(t0 + 32 + c32) * HDc + koff];
                    s0 = __builtin_amdgcn_mfma_f32_32x32x16_bf16(kf0, qf[ko], s0, 0, 0, 0);
                    s1 = __builtin_amdgcn_mfma_f32_32x32x16_bf16(kf1, qf[ko], s1, 0, 0, 0);
                }
                float v[32];
#pragma unroll
                for (int r = 0; r < 16; r++) { v[r] = s0[r]; v[16 + r] = s1[r]; }
#pragma unroll
                for (int i = 0; i < 32; i++) v[i] = exp2f(v[i] * CEXP);
                unsigned pk[16];
#pragma unroll
                for (int i = 0; i < 16; i++) pk[i] = pack2bf(v[2 * i], v[2 * i + 1]);
#pragma unroll
                for (int st = 1; st < 32; st <<= 1)
#pragma unroll
                    for (int i = 0; i < 32; i += 2 * st) v[i] += v[i + st];
                lacc += v[0];
#pragma unroll
                for (int ko = 0; ko < 4; ko++) {
                    const int a = (ko >> 1) * 8 + (ko & 1) * 4;
                    unsigned keep0 = h ? pk[a + 2] : pk[a + 0];
                    unsigned keep1 = h ? pk[a + 3] : pk[a + 1];
                    unsigned send0 = h ? pk[a + 0] : pk[a + 2];
                    unsigned send1 = h ? pk[a + 1] : pk[a + 3];
                    unsigned recv0 = (unsigned)__shfl_xor((int)send0, 32);
                    unsigned recv1 = (unsigned)__shfl_xor((int)send1, 32);
                    union { bf16x8 v8; unsigned u[4]; } pf;
                    pf.u[0] = h ? recv0 : keep0;
                    pf.u[1] = h ? recv1 : keep1;
                    pf.u[2] = h ? keep0 : recv0;
                    pf.u[3] = h ? keep1 : recv1;
                    const int oct = ko * 2 + h;
                    bf16x8 vf0 = *(const bf16x8*)&Vt[qkbase + (size_t)c32 * Tc + t0 + oct * 8];
                    bf16x8 vf1 = *(const bf16x8*)&Vt[qkbase + (size_t)(32 + c32) * Tc + t0 + oct * 8];
                    acc0 = __builtin_amdgcn_mfma_f32_32x32x16_bf16(vf0, pf.v8, acc0, 0, 0, 0);
                    acc1 = __builtin_amdgcn_mfma_f32_32x32x16_bf16(vf1, pf.v8, acc1, 0, 0, 0);
                }
            }

            const float lfull = lacc + __shfl_xor(lacc, 32);
            if (h == 0) s_lm[wave * 32 + c32] = lfull;
#pragma unroll
            for (int r = 0; r < 16; r++) {
                const int d = (r & 3) + 8 * (r >> 2) + 4 * h;
                s_accm[(wave * 64 + d) * 32 + c32] = acc0[r];
                s_accm[(wave * 64 + 32 + d) * 32 + c32] = acc1[r];
            }
            __syncthreads();
            for (int i = tid; i < 2048; i += 256) {
                const int sl = i >> 6, d = i & 63;
                if (pass * 32 + sl < cnt) {
                    const float o = s_accm[(0 * 64 + d) * 32 + sl] + s_accm[(1 * 64 + d) * 32 + sl] +
                                    s_accm[(2 * 64 + d) * 32 + sl] + s_accm[(3 * 64 + d) * 32 + sl];
                    const float lt = s_lm[sl] + s_lm[32 + sl] + s_lm[64 + sl] + s_lm[96 + sl];
                    const int qrow = s_list[pass * 32 + sl];
                    AO[((size_t)(b * Tc + qrow)) * Dc + hd * HDc + d] = f2bf(o / lt);
                }
            }
            __syncthreads();
        }
        return;
    }

    // ============ causal path: 2-way key-split + fixed-max softmax ============
    unsigned short* KV = (unsigned short*)smem;
    unsigned short* Ke = KV;                       // even-tile K (8 KB)
    unsigned short* Ko = KV + 4096;                // odd-tile  K
    unsigned short* Ve = KV + 8192;                // even-tile V^T
    unsigned short* Vo = KV + 12288;               // odd-tile  V^T

    const int idx = blk - 32;                      // 0..1023
    const int bh = (idx & 7) + 8 * ((idx >> 3) & 3);   // 4 bh per XCD
    const int b = bh >> 4;
    const int hd = bh & 15;
    // weight index -> j so stride-8 samples {w, w+8, w+16, w+24} (one CU's 4
    // resident blocks) give j = {u, 31-u, 8+u, 23-u}: nTiles sum == 66 const.
    const int w = idx >> 5;                        // 0..31
    const int u = w & 7, tq = w >> 3;
    const int j = (tq == 0) ? u : (tq == 1) ? 31 - u : (tq == 2) ? 8 + u : 23 - u;
    const int qb0 = j * 64;
    const int nT = j + 1;                          // 64-key tiles in [0, qb0+64)
    const int wq0 = qb0 + (wave & 1) * 32;         // wave's 32 q rows
    const size_t qkbase = (size_t)bh * Tc * HDc;
    const int q = wq0 + c32;

    // Q B-fragments (whole kernel): B[k=hd=ko*16+h*8+j][n=q=c32]
    bf16x8 qf[4];
#pragma unroll
    for (int ko = 0; ko < 4; ko++)
        qf[ko] = *(const bf16x8*)&Q[qkbase + (size_t)q * HDc + ko * 16 + h * 8];

    const int myid = ids[b * Tc + q];
    const bool gr = ((unsigned)(myid - 2) <= 5u);  // global row: store suppressed

    f32x16 acc0 = {}, acc1 = {};
    float lacc = 0.0f;

    // staging constants (global_load_lds: linear LDS, pre-swizzled source)
    const int lrow = lane >> 3;                    // 0..7
    const int srcoct = (lane & 7) ^ lrow;          // source oct for this lane
    const int jb = wave * 2;                       // wave's 1-KB chunk base

    auto stageK = [&](int t0, unsigned short* buf) {
#pragma unroll
        for (int i = 0; i < 2; i++) {
            const int jj = jb + i;                 // 0..7 (8 x 1 KB = 8 KB)
            const int row = jj * 8 + lrow;         // key row 0..63
            gload_lds16(&K[qkbase + (size_t)(t0 + row) * HDc + srcoct * 8],
                        &buf[jj * 512]);
        }
    };
    auto stageV = [&](int t0, unsigned short* buf) {
#pragma unroll
        for (int i = 0; i < 2; i++) {
            const int jj = jb + i;
            const int d = jj * 8 + lrow;           // d row 0..63
            gload_lds16(&Vt[qkbase + (size_t)d * Tc + t0 + srcoct * 8],
                        &buf[jj * 512]);
        }
    };

    auto computeT = [&](int t0, const unsigned short* Kb, const unsigned short* Vb) {
        // --- scores S^T[key][q]: 2 key-tiles of 32, contraction 64 = 4 MFMAs
        f32x16 s0 = {}, s1 = {};
#pragma unroll
        for (int ko = 0; ko < 4; ko++) {
            const int oct = ko * 2 + h;
            const int k0i = c32;
            const int k1i = 32 + c32;
            bf16x8 kf0 = *(const bf16x8*)&Kb[(k0i * 8 + (oct ^ (k0i & 7))) * 8];
            bf16x8 kf1 = *(const bf16x8*)&Kb[(k1i * 8 + (oct ^ (k1i & 7))) * 8];
            s0 = __builtin_amdgcn_mfma_f32_32x32x16_bf16(kf0, qf[ko], s0, 0, 0, 0);
            s1 = __builtin_amdgcn_mfma_f32_32x32x16_bf16(kf1, qf[ko], s1, 0, 0, 0);
        }

        // --- fixed-max softmax: p = exp2(s*CEXP), no chains, no cross-lane
        float v[32];
#pragma unroll
        for (int r = 0; r < 16; r++) { v[r] = s0[r]; v[16 + r] = s1[r]; }
#pragma unroll
        for (int i = 0; i < 32; i++) v[i] = exp2f(v[i] * CEXP);

        const bool needMask = (t0 + 63 > wq0);     // wave-uniform (diag tile)
        if (needMask) {
            const int thr = wq0 + c32 - t0 - 4 * h;
#pragma unroll
            for (int kt = 0; kt < 2; kt++)
#pragma unroll
                for (int r = 0; r < 16; r++) {
                    const int ckr = kt * 32 + (r & 3) + 8 * (r >> 2);
                    v[kt * 16 + r] = (ckr <= thr) ? v[kt * 16 + r] : 0.0f;
                }
        }

        unsigned pk[16];
#pragma unroll
        for (int i = 0; i < 16; i++) pk[i] = pack2bf(v[2 * i], v[2 * i + 1]);

        // l accumulation: depth-5 pairwise tree, no cross-lane op
#pragma unroll
        for (int st = 1; st < 32; st <<= 1)
#pragma unroll
            for (int i = 0; i < 32; i += 2 * st) v[i] += v[i + st];
        lacc += v[0];

        // --- PV: O^T += V^T x P^T
#pragma unroll
        for (int ko = 0; ko < 4; ko++) {
            const int a = (ko >> 1) * 8 + (ko & 1) * 4;
            unsigned keep0 = h ? pk[a + 2] : pk[a + 0];
            unsigned keep1 = h ? pk[a + 3] : pk[a + 1];
            unsigned send0 = h ? pk[a + 0] : pk[a + 2];
            unsigned send1 = h ? pk[a + 1] : pk[a + 3];
            unsigned recv0 = (unsigned)__shfl_xor((int)send0, 32);
            unsigned recv1 = (unsigned)__shfl_xor((int)send1, 32);
            union { bf16x8 v8; unsigned u[4]; } pf;
            pf.u[0] = h ? recv0 : keep0;
            pf.u[1] = h ? recv1 : keep1;
            pf.u[2] = h ? keep0 : recv0;
            pf.u[3] = h ? keep1 : recv1;
            const int oct = ko * 2 + h;
            const int d0 = c32, d1 = 32 + c32;
            bf16x8 vf0 = *(const bf16x8*)&Vb[(d0 * 8 + (oct ^ (d0 & 7))) * 8];
            bf16x8 vf1 = *(const bf16x8*)&Vb[(d1 * 8 + (oct ^ (d1 & 7))) * 8];
            acc0 = __builtin_amdgcn_mfma_f32_32x32x16_bf16(vf0, pf.v8, acc0, 0, 0, 0);
            acc1 = __builtin_amdgcn_mfma_f32_32x32x16_bf16(vf1, pf.v8, acc1, 0, 0, 0);
        }
    };

    // K-loop over tile pairs: stage (even,odd) -> group A even, group B odd
    for (int tp = 0; tp < nT; tp += 2) {
        __syncthreads();                           // prior pair's reads done
        stageK(tp * 64, Ke);
        stageV(tp * 64, Ve);
        const bool has2 = (tp + 1) < nT;
        if (has2) {
            stageK((tp + 1) * 64, Ko);
            stageV((tp + 1) * 64, Vo);
        }
        __syncthreads();                           // drains vmcnt: pair ready
        if ((wave >> 1) == 0) computeT(tp * 64, Ke, Ve);
        else if (has2) computeT((tp + 1) * 64, Ko, Vo);
    }

    // --- merge key-split partials: wave 2->0, 3->1 via LDS ([r][lane]: no
    // bank conflicts), then h-halves of l, then store.
    __syncthreads();
    float* mrg = smem + (wave & 1) * 2176;         // 2 pairs x 2176 f32
    if (wave >= 2) {
#pragma unroll
        for (int r = 0; r < 16; r++) {
            mrg[r * 64 + lane] = acc0[r];
            mrg[(16 + r) * 64 + lane] = acc1[r];
        }
        mrg[2048 + lane] = lacc;
    }
    __syncthreads();
    if (wave >= 2) return;
#pragma unroll
    for (int r = 0; r < 16; r++) {
        acc0[r] += mrg[r * 64 + lane];
        acc1[r] += mrg[(16 + r) * 64 + lane];
    }
    lacc += mrg[2048 + lane];

    const float l = lacc + __shfl_xor(lacc, 32);
    if (!gr) {
        const float inv = 1.0f / l;
        unsigned short* dst = &AO[((size_t)(b * Tc + q)) * Dc + hd * HDc];
#pragma unroll
        for (int i = 0; i < 8; i++) {
            const int r = 2 * i;
            const int d = (r & 3) + 8 * (r >> 2) + 4 * h;
            *(unsigned*)&dst[d]      = pack2bf(acc0[r] * inv, acc0[r + 1] * inv);
            *(unsigned*)&dst[32 + d] = pack2bf(acc1[r] * inv, acc1[r + 1] * inv);
        }
    }
}

// ---------------------------------------------------------------------------
extern "C" void kernel_launch(void* const* d_in, const int* in_sizes, int n_in,
                              void* d_out, int out_size, void* d_ws, size_t ws_size,
                              hipStream_t stream)
{
    const float* x    = (const float*)d_in[0];
    const int*   ids  = (const int*)d_in[1];
    const float* Wqkv = (const float*)d_in[2];
    const float* bqkv = (const float*)d_in[3];
    const float* Wout = (const float*)d_in[4];
    const float* bout = (const float*)d_in[5];
    float* out = (float*)d_out;

    const size_t TEN = (size_t)Bc * Hc * Tc * HDc;   // 4,194,304 elements
    unsigned short* xb    = (unsigned short*)d_ws;            // 4.2M us
    unsigned short* wqkvb = xb + 4194304;                     // 3.1M us
    unsigned short* woutb = wqkvb + 3145728;                  // 1.0M us
    float2* ropeTab       = (float2*)(woutb + 1048576);       // 64K float2
    unsigned short* Qb    = (unsigned short*)(ropeTab + 65536);
    unsigned short* Kb    = Qb + TEN;
    unsigned short* Vtb   = Kb + TEN;
    unsigned short* AOb   = Vtb + TEN;                        // ~51 MB total

    // 0. fp32 -> bf16 conversions + RoPE table (grid-stride x4)
    convert_bf16<<<2048, 256, 0, stream>>>(x, Wqkv, Wout, xb, wqkvb, woutb,
                                           ropeTab);
    // 1. QKV projection (MFMA) + fused RoPE -> bf16 Q/K [b,h,t,d], V^T [b,h,d,t]
    dim3 g1(3072 / 128, 4096 / 128);
    gemm_mfma<1, 4, 4><<<g1, 256, 0, stream>>>(xb, wqkvb, bqkv, nullptr,
                                               Qb, Kb, Vtb, ropeTab,
                                               4096, 3072, 1024);
    // 2. attention (R2 key-split causal + global path) -> bf16 AO
    attn_fused<<<1056, 256, 0, stream>>>(Qb, Kb, Vtb, ids, AOb);
    // 3. output projection (MFMA, fp32 out) — 64x64 tiles, 1024 blocks = 4/CU
    dim3 g4(1024 / 64, 4096 / 64);
    gemm_mfma<0, 2, 2><<<g4, 256, 0, stream>>>(AOb, woutb, bout, out,
                                               nullptr, nullptr, nullptr, nullptr,
                                               4096, 1024, 1024);
}

// Round 9
// 192.521 us; speedup vs baseline: 1.2213x; 1.0049x over previous
//
#include <hip/hip_runtime.h>
#include <math.h>

// Problem constants
#define Bc 2
#define Tc 2048
#define Dc 1024
#define Hc 16
#define HDc 64
// M = B*T = 4096, QKV N = 3072, K = 1024

typedef __attribute__((ext_vector_type(8))) short bf16x8;
typedef __attribute__((ext_vector_type(4))) float f32x4;
typedef __attribute__((ext_vector_type(16))) float f32x16;

__device__ __forceinline__ unsigned short f2bf(float f) {
    union { float f; unsigned int u; } v; v.f = f;
    unsigned int r = (v.u + 0x7FFFu + ((v.u >> 16) & 1u)) >> 16;   // RNE
    return (unsigned short)r;
}
// pack two fp32 -> bf16x2 dword (round-nearest, ties up): 3 VALU
__device__ __forceinline__ unsigned pack2bf(float a, float b) {
    unsigned au = __float_as_uint(a) + 0x8000u;
    unsigned bu = __float_as_uint(b) + 0x8000u;
    return __builtin_amdgcn_perm(bu, au, 0x07060302u);
}

// async global->LDS, 16 B per lane. LDS dest is WAVE-UNIFORM base + lane*16.
__device__ __forceinline__ void gload_lds16(const unsigned short* g,
                                            unsigned short* l) {
    __builtin_amdgcn_global_load_lds(
        (const __attribute__((address_space(1))) unsigned int*)g,
        (__attribute__((address_space(3))) unsigned int*)l,
        16, 0, 0);
}

// exp scale: 1/sqrt(64) * log2(e)  (fixed-max softmax: p = exp2(s*CEXP))
#define CEXP 0.1803368801111204f

// ---------------------------------------------------------------------------
// fp32 -> bf16 conversion for x, W_qkv, W_out + RoPE cos/sin table fill.
// Grid-stride (G11): 2048 blocks x 4 iterations of float4.
// ---------------------------------------------------------------------------
__global__ __launch_bounds__(256) void convert_bf16(
    const float* __restrict__ x, const float* __restrict__ wqkv,
    const float* __restrict__ wout,
    unsigned short* __restrict__ xb, unsigned short* __restrict__ wqkvb,
    unsigned short* __restrict__ woutb, float2* __restrict__ ropeTab)
{
    const int gid = blockIdx.x * 256 + threadIdx.x;      // 0..524287
    // RoPE table: 2048 x 32 entries (cos, sin), angle = t * 10000^(-i/32)
    if (gid < Tc * 32) {
        const int t = gid >> 5, i = gid & 31;
        const float freq = exp2f((float)i * -0.4152410118609203f);
        const float ang = (float)t * freq;
        ropeTab[gid] = make_float2(cosf(ang), sinf(ang));
    }
#pragma unroll
    for (int it = 0; it < 4; it++) {
        const int i = (it * 524288 + gid) * 4;           // 8,388,608 floats
        const float* src; unsigned short* dst; int off;
        if (i < 4194304)      { src = x;    dst = xb;    off = i; }
        else if (i < 7340032) { src = wqkv; dst = wqkvb; off = i - 4194304; }
        else                  { src = wout; dst = woutb; off = i - 7340032; }
        float4 v = *(const float4*)&src[off];
        ushort4 o;
        o.x = f2bf(v.x); o.y = f2bf(v.y); o.z = f2bf(v.z); o.w = f2bf(v.w);
        *(ushort4*)&dst[off] = o;
    }
}

// ---------------------------------------------------------------------------
// bf16 MFMA GEMM:  C[M,N] = A[M,K] @ W[N,K]^T + bias[N]
// Block tile (MT*32) x (NT*32), BK=64, 256 thr = 4 waves (2x2),
// per-wave tile (MT*16) x (NT*16) frags of 16x16x32.
//   <1,4,4>: 128x128 QKV + fused RoPE epilogue (Q/K [b,h,t,d]; V^T [b,h,d,t])
//   <0,2,2>: 64x64 out-proj (fp32 C + bias) — grid 1024 blocks = 4/CU
// NO XCD remap (R7 lesson): the flat%8 band remap raised QKV 50->66us with
// FETCH unchanged — default x-fast order already gives each XCD consecutive
// same-A-panel blocks; the remap destroyed that. Default blockIdx mapping.
// Staging: async global_load_lds width=16 (linear LDS dest), global source
// oct PRE-SWIZZLED so LDS[r][o] = G[r][o ^ (r&7)] -> fragment reads stay
// 2-way-conflict-free.
// ---------------------------------------------------------------------------
template <int MODE, int MT, int NT>
__global__ __launch_bounds__(256) void gemm_mfma(
    const unsigned short* __restrict__ A, const unsigned short* __restrict__ W,
    const float* __restrict__ bias, float* __restrict__ C,
    unsigned short* __restrict__ Qp, unsigned short* __restrict__ Kp,
    unsigned short* __restrict__ Vtp, const float2* __restrict__ ropeTab,
    int M, int N, int K)
{
    __shared__ unsigned short Apk[MT * 32 * 64];
    __shared__ unsigned short Bpk[NT * 32 * 64];

    const int tid = threadIdx.x;
    const int lane = tid & 63;
    const int wave = tid >> 6;
    const int quad = lane >> 4;
    const int c = lane & 15;
    const int wm = wave >> 1;
    const int wn = wave & 1;
    const int m0 = blockIdx.y * (MT * 32);
    const int n0 = blockIdx.x * (NT * 32);

    f32x4 acc[MT][NT];
#pragma unroll
    for (int mt = 0; mt < MT; mt++)
#pragma unroll
        for (int nt = 0; nt < NT; nt++) acc[mt][nt] = (f32x4){0.f, 0.f, 0.f, 0.f};

    // staging: wave-load of 1 KB covers 8 rows x 8 octs. lane -> (row, oct):
    // row_in_chunk = lane>>3, lds oct = lane&7 (fixed by HW linear layout).
    // source oct = (lane&7) ^ (r&7); r&7 == lane>>3 for all 8-aligned chunks.
    const int lrow = lane >> 3;
    const int srcoct = (lane & 7) ^ lrow;

    for (int k0 = 0; k0 < K; k0 += 64) {
        __syncthreads();                       // prior tile's ds_reads done
#pragma unroll
        for (int i = 0; i < MT; i++) {
            const int r = wave * (MT * 8) + i * 8 + lrow;
            gload_lds16(&A[(size_t)(m0 + r) * K + k0 + srcoct * 8],
                        &Apk[(wave * MT * 8 + i * 8) * 64]);
        }
#pragma unroll
        for (int i = 0; i < NT; i++) {
            const int r = wave * (NT * 8) + i * 8 + lrow;
            gload_lds16(&W[(size_t)(n0 + r) * K + k0 + srcoct * 8],
                        &Bpk[(wave * NT * 8 + i * 8) * 64]);
        }
        __syncthreads();                       // drains vmcnt(0): tile ready
#pragma unroll
        for (int ko = 0; ko < 2; ko++) {
            bf16x8 af[MT], bf[NT];
#pragma unroll
            for (int mt = 0; mt < MT; mt++) {
                const int m = wm * (MT * 16) + mt * 16 + c;
                af[mt] = *(const bf16x8*)&Apk[(m * 8 + ((ko * 4 + quad) ^ (m & 7))) * 8];
            }
#pragma unroll
            for (int nt = 0; nt < NT; nt++) {
                const int n = wn * (NT * 16) + nt * 16 + c;
                bf[nt] = *(const bf16x8*)&Bpk[(n * 8 + ((ko * 4 + quad) ^ (n & 7))) * 8];
            }
#pragma unroll
            for (int mt = 0; mt < MT; mt++)
#pragma unroll
                for (int nt = 0; nt < NT; nt++)
                    acc[mt][nt] = __builtin_amdgcn_mfma_f32_16x16x32_bf16(
                        af[mt], bf[nt], acc[mt][nt], 0, 0, 0);
        }
    }

    if (MODE == 0) {
#pragma unroll
        for (int mt = 0; mt < MT; mt++) {
            const int m = m0 + wm * (MT * 16) + mt * 16 + quad * 4;
#pragma unroll
            for (int nt = 0; nt < NT; nt++) {
                const int n = n0 + wn * (NT * 16) + nt * 16 + c;
                const float bv = bias[n];
#pragma unroll
                for (int reg = 0; reg < 4; reg++)
                    C[(size_t)(m + reg) * N + n] = acc[mt][nt][reg] + bv;
            }
        }
    } else {
        const int n_wave = n0 + wn * 64;          // 64-aligned -> one head/wave
        const int which = n_wave >> 10;           // 0=q,1=k,2=v (block-uniform)
        const int h = (n_wave >> 6) & 15;
        const int b = m0 >> 11;
        const int t_base = (m0 & 2047) + wm * 64;

        __syncthreads();   // all MFMA LDS reads done; reuse Apk/Bpk as staging
        // per-wave 8-KB staging region (wave-private; DS ops in-order per wave)
        unsigned short* stg = ((wave < 2) ? Apk : Bpk) + (wave & 1) * 4096;

        if (which < 2) {
            // ---- Q/K with fused RoPE: rotate -> LDS tile -> coalesced store
            unsigned short* dst = (which == 0) ? Qp : Kp;
#pragma unroll
            for (int mt = 0; mt < 4; mt++) {
#pragma unroll
                for (int nt = 0; nt < 2; nt++) {
                    const int i1 = nt * 16 + c;            // rotary index 0..31
                    const float bv1 = bias[n_wave + i1];
                    const float bv2 = bias[n_wave + 32 + i1];
#pragma unroll
                    for (int reg = 0; reg < 4; reg++) {
                        const int row = mt * 16 + quad * 4 + reg;
                        const float2 cs = ropeTab[(t_base + row) * 32 + i1];
                        const float x1 = acc[mt][nt][reg] + bv1;
                        const float x2 = acc[mt][nt + 2][reg] + bv2;
                        const int col2 = 32 + i1;
                        stg[(row * 8 + ((i1 >> 3) ^ (row & 7))) * 8 + (i1 & 7)] =
                            f2bf(x1 * cs.x - x2 * cs.y);
                        stg[(row * 8 + ((col2 >> 3) ^ (row & 7))) * 8 + (col2 & 7)] =
                            f2bf(x1 * cs.y + x2 * cs.x);
                    }
                }
            }
            // tile [t_base..t_base+63][0..63] is 8 KB CONTIGUOUS in Q/K
            const size_t obase = ((size_t)(b * Hc + h) * Tc + t_base) * HDc;
            const int oct = lane & 7;
#pragma unroll
            for (int k = 0; k < 8; k++) {
                const int f = lane * 8 + k * 512;       // flat ushort offset
                const int row = f >> 6;
                bf16x8 vv = *(const bf16x8*)&stg[(row * 8 + (oct ^ (row & 7))) * 8];
                *(bf16x8*)&dst[obase + f] = vv;         // 64 lanes x 16 B = 1 KB
            }
        } else {
            // ---- V: stage transposed tile [d][t], store full 128-B d-rows
#pragma unroll
            for (int mt = 0; mt < 4; mt++) {
#pragma unroll
                for (int nt = 0; nt < 4; nt++) {
                    const int d = nt * 16 + c;
                    const float bv = bias[n_wave + d];
#pragma unroll
                    for (int reg = 0; reg < 4; reg++) {
                        const int r = mt * 16 + quad * 4 + reg;   // t within tile
                        stg[(d * 8 + ((r >> 3) ^ (d & 7))) * 8 + (r & 7)] =
                            f2bf(acc[mt][nt][reg] + bv);
                    }
                }
            }
            const size_t vbase = (size_t)(b * Hc + h) * HDc * Tc;
            const int oct = lane & 7;                   // t-chunk
#pragma unroll
            for (int k = 0; k < 8; k++) {
                const int d = (lane >> 3) + k * 8;
                bf16x8 vv = *(const bf16x8*)&stg[(d * 8 + (oct ^ (d & 7))) * 8];
                // 8 lanes cover one full 128-B line per d-row
                *(bf16x8*)&Vtp[vbase + (size_t)d * Tc + t_base + oct * 8] = vv;
            }
        }
    }
}

// ---------------------------------------------------------------------------
// Fused attention. Grid = 1056 blocks:
//   blk 0..31    : global-query rows (full-T, one block per bh).
//   blk 32..1055 : causal, 2-way KEY-SPLIT (fixed-max softmax => O,l partials
//     are linear and just add): each block owns 64 q rows of one bh;
//     waves {0,1} compute EVEN 64-key tiles, waves {2,3} ODD tiles;
//     partials merged via LDS at the end.
//   UNTESTED MATRIX CELL (R2/R3/R5): forced (256,4) occupancy (+10.8us,
//   R2 vs R5) x 2-phase pipeline (+4.6us, R3 vs R5). Schedule per pair:
//       barrier -> stage V(pair) -> QK^T+softmax (V in flight)
//       barrier -> stage K(next pair) -> PV (K in flight)
//   2 barriers/pair as R2. Fallback if this regresses vs 52.8: R2 loop
//   (stage K+V -> barrier -> compute) with same (256,4).
// ---------------------------------------------------------------------------
__global__ __launch_bounds__(256, 4) void attn_fused(
    const unsigned short* __restrict__ Q, const unsigned short* __restrict__ K,
    const unsigned short* __restrict__ Vt, const int* __restrict__ ids,
    unsigned short* __restrict__ AO)
{
    __shared__ __align__(16) float smem[8448];   // 33792 B, overlaid per path

    const int tid = threadIdx.x;
    const int lane = tid & 63;
    const int wave = tid >> 6;
    const int c32 = lane & 31;
    const int h = lane >> 5;
    const int blk = blockIdx.x;

    if (blk < 32) {
        // ================= global-query rows =================
        int* s_list = (int*)smem;                 // 64
        int* s_cnt = (int*)smem + 64;
        float* s_accm = smem + 128;               // [4][64][32]
        float* s_lm = s_accm + 8192;              // [4][32]

        const int bh = blk;
        const int b = bh >> 4;
        const int hd = bh & 15;
        const size_t qkbase = (size_t)bh * Tc * HDc;

        if (tid == 0) *s_cnt = 0;
        __syncthreads();
        for (int i = tid; i < Tc; i += 256) {
            int id = ids[b * Tc + i];
            if ((unsigned)(id - 2) <= 5u) {
                int p = atomicAdd(s_cnt, 1);
                if (p < 64) s_list[p] = i;
            }
        }
        __syncthreads();
        const int cnt = min(*s_cnt, 64);

        for (int pass = 0; pass * 32 < cnt; pass++) {
            const int slot = pass * 32 + c32;
            const int row = (slot < cnt) ? s_list[slot] : s_list[0];

            bf16x8 qf[4];
#pragma unroll
            for (int ko = 0; ko < 4; ko++)
                qf[ko] = *(const bf16x8*)&Q[qkbase + (size_t)row * HDc + ko * 16 + h * 8];

            f32x16 acc0 = {}, acc1 = {};
            float lacc = 0.0f;

            for (int it = wave; it < Tc / 64; it += 4) {
                const int t0 = it * 64;
                f32x16 s0 = {}, s1 = {};
#pragma unroll
                for (int ko = 0; ko < 4; ko++) {
                    const int koff = ko * 16 + h * 8;
                    bf16x8 kf0 = *(const bf16x8*)&K[qkbase + (size_t)(t0 + c32) * HDc + koff];
                    bf16x8 kf1 = *(const bf16x8*)&K[qkbase + (size_t)(t0 + 32 + c32) * HDc + koff];
                    s0 = __builtin_amdgcn_mfma_f32_32x32x16_bf16(kf0, qf[ko], s0, 0, 0, 0);
                    s1 = __builtin_amdgcn_mfma_f32_32x32x16_bf16(kf1, qf[ko], s1, 0, 0, 0);
                }
                float v[32];
#pragma unroll
                for (int r = 0; r < 16; r++) { v[r] = s0[r]; v[16 + r] = s1[r]; }
#pragma unroll
                for (int i = 0; i < 32; i++) v[i] = exp2f(v[i] * CEXP);
                unsigned pk[16];
#pragma unroll
                for (int i = 0; i < 16; i++) pk[i] = pack2bf(v[2 * i], v[2 * i + 1]);
#pragma unroll
                for (int st = 1; st < 32; st <<= 1)
#pragma unroll
                    for (int i = 0; i < 32; i += 2 * st) v[i] += v[i + st];
                lacc += v[0];
#pragma unroll
                for (int ko = 0; ko < 4; ko++) {
                    const int a = (ko >> 1) * 8 + (ko & 1) * 4;
                    unsigned keep0 = h ? pk[a + 2] : pk[a + 0];
                    unsigned keep1 = h ? pk[a + 3] : pk[a + 1];
                    unsigned send0 = h ? pk[a + 0] : pk[a + 2];
                    unsigned send1 = h ? pk[a + 1] : pk[a + 3];
                    unsigned recv0 = (unsigned)__shfl_xor((int)send0, 32);
                    unsigned recv1 = (unsigned)__shfl_xor((int)send1, 32);
                    union { bf16x8 v8; unsigned u[4]; } pf;
                    pf.u[0] = h ? recv0 : keep0;
                    pf.u[1] = h ? recv1 : keep1;
                    pf.u[2] = h ? keep0 : recv0;
                    pf.u[3] = h ? keep1 : recv1;
                    const int oct = ko * 2 + h;
                    bf16x8 vf0 = *(const bf16x8*)&Vt[qkbase + (size_t)c32 * Tc + t0 + oct * 8];
                    bf16x8 vf1 = *(const bf16x8*)&Vt[qkbase + (size_t)(32 + c32) * Tc + t0 + oct * 8];
                    acc0 = __builtin_amdgcn_mfma_f32_32x32x16_bf16(vf0, pf.v8, acc0, 0, 0, 0);
                    acc1 = __builtin_amdgcn_mfma_f32_32x32x16_bf16(vf1, pf.v8, acc1, 0, 0, 0);
                }
            }

            const float lfull = lacc + __shfl_xor(lacc, 32);
            if (h == 0) s_lm[wave * 32 + c32] = lfull;
#pragma unroll
            for (int r = 0; r < 16; r++) {
                const int d = (r & 3) + 8 * (r >> 2) + 4 * h;
                s_accm[(wave * 64 + d) * 32 + c32] = acc0[r];
                s_accm[(wave * 64 + 32 + d) * 32 + c32] = acc1[r];
            }
            __syncthreads();
            for (int i = tid; i < 2048; i += 256) {
                const int sl = i >> 6, d = i & 63;
                if (pass * 32 + sl < cnt) {
                    const float o = s_accm[(0 * 64 + d) * 32 + sl] + s_accm[(1 * 64 + d) * 32 + sl] +
                                    s_accm[(2 * 64 + d) * 32 + sl] + s_accm[(3 * 64 + d) * 32 + sl];
                    const float lt = s_lm[sl] + s_lm[32 + sl] + s_lm[64 + sl] + s_lm[96 + sl];
                    const int qrow = s_list[pass * 32 + sl];
                    AO[((size_t)(b * Tc + qrow)) * Dc + hd * HDc + d] = f2bf(o / lt);
                }
            }
            __syncthreads();
        }
        return;
    }

    // ====== causal path: key-split + (256,4) + 2-phase pipelined staging =====
    unsigned short* KV = (unsigned short*)smem;
    unsigned short* Ke = KV;                       // even-tile K (8 KB)
    unsigned short* Ko = KV + 4096;                // odd-tile  K
    unsigned short* Ve = KV + 8192;                // even-tile V^T
    unsigned short* Vo = KV + 12288;               // odd-tile  V^T

    const int idx = blk - 32;                      // 0..1023
    const int bh = (idx & 7) + 8 * ((idx >> 3) & 3);   // 4 bh per XCD
    const int b = bh >> 4;
    const int hd = bh & 15;
    // weight index -> j so stride-8 samples {w, w+8, w+16, w+24} (one CU's 4
    // resident blocks) give j = {u, 31-u, 8+u, 23-u}: nTiles sum == 66 const.
    const int w = idx >> 5;                        // 0..31
    const int u = w & 7, tq = w >> 3;
    const int j = (tq == 0) ? u : (tq == 1) ? 31 - u : (tq == 2) ? 8 + u : 23 - u;
    const int qb0 = j * 64;
    const int nT = j + 1;                          // 64-key tiles in [0, qb0+64)
    const int grp = wave >> 1;                     // 0: even tiles, 1: odd
    const int wq0 = qb0 + (wave & 1) * 32;         // wave's 32 q rows
    const size_t qkbase = (size_t)bh * Tc * HDc;
    const int q = wq0 + c32;

    // Q B-fragments (whole kernel): B[k=hd=ko*16+h*8+j][n=q=c32]
    bf16x8 qf[4];
#pragma unroll
    for (int ko = 0; ko < 4; ko++)
        qf[ko] = *(const bf16x8*)&Q[qkbase + (size_t)q * HDc + ko * 16 + h * 8];

    const int myid = ids[b * Tc + q];
    const bool gr = ((unsigned)(myid - 2) <= 5u);  // global row: store suppressed

    f32x16 acc0 = {}, acc1 = {};
    float lacc = 0.0f;

    // staging constants (global_load_lds: linear LDS, pre-swizzled source)
    const int lrow = lane >> 3;                    // 0..7
    const int srcoct = (lane & 7) ^ lrow;          // source oct for this lane
    const int jb = wave * 2;                       // wave's 1-KB chunk base

    auto stageK = [&](int t0, unsigned short* buf) {
#pragma unroll
        for (int i = 0; i < 2; i++) {
            const int jj = jb + i;                 // 0..7 (8 x 1 KB = 8 KB)
            const int row = jj * 8 + lrow;         // key row 0..63
            gload_lds16(&K[qkbase + (size_t)(t0 + row) * HDc + srcoct * 8],
                        &buf[jj * 512]);
        }
    };
    auto stageV = [&](int t0, unsigned short* buf) {
#pragma unroll
        for (int i = 0; i < 2; i++) {
            const int jj = jb + i;
            const int d = jj * 8 + lrow;           // d row 0..63
            gload_lds16(&Vt[qkbase + (size_t)d * Tc + t0 + srcoct * 8],
                        &buf[jj * 512]);
        }
    };

    unsigned pk[16];

    auto qkPhase = [&](int t0, const unsigned short* Kb) {
        // --- scores S^T[key][q]: 2 key-tiles of 32, contraction 64 = 4 MFMAs
        f32x16 s0 = {}, s1 = {};
#pragma unroll
        for (int ko = 0; ko < 4; ko++) {
            const int oct = ko * 2 + h;
            const int k0i = c32;
            const int k1i = 32 + c32;
            bf16x8 kf0 = *(const bf16x8*)&Kb[(k0i * 8 + (oct ^ (k0i & 7))) * 8];
            bf16x8 kf1 = *(const bf16x8*)&Kb[(k1i * 8 + (oct ^ (k1i & 7))) * 8];
            s0 = __builtin_amdgcn_mfma_f32_32x32x16_bf16(kf0, qf[ko], s0, 0, 0, 0);
            s1 = __builtin_amdgcn_mfma_f32_32x32x16_bf16(kf1, qf[ko], s1, 0, 0, 0);
        }

        // --- fixed-max softmax: p = exp2(s*CEXP), no chains, no cross-lane
        float v[32];
#pragma unroll
        for (int r = 0; r < 16; r++) { v[r] = s0[r]; v[16 + r] = s1[r]; }
#pragma unroll
        for (int i = 0; i < 32; i++) v[i] = exp2f(v[i] * CEXP);

        const bool needMask = (t0 + 63 > wq0);     // wave-uniform (diag tile)
        if (needMask) {
            const int thr = wq0 + c32 - t0 - 4 * h;
#pragma unroll
            for (int kt = 0; kt < 2; kt++)
#pragma unroll
                for (int r = 0; r < 16; r++) {
                    const int ckr = kt * 32 + (r & 3) + 8 * (r >> 2);
                    v[kt * 16 + r] = (ckr <= thr) ? v[kt * 16 + r] : 0.0f;
                }
        }

#pragma unroll
        for (int i = 0; i < 16; i++) pk[i] = pack2bf(v[2 * i], v[2 * i + 1]);

        // l accumulation: depth-5 pairwise tree, no cross-lane op
#pragma unroll
        for (int st = 1; st < 32; st <<= 1)
#pragma unroll
            for (int i = 0; i < 32; i += 2 * st) v[i] += v[i + st];
        lacc += v[0];
    };

    auto pvPhase = [&](const unsigned short* Vb) {
        // --- PV: O^T += V^T x P^T
#pragma unroll
        for (int ko = 0; ko < 4; ko++) {
            const int a = (ko >> 1) * 8 + (ko & 1) * 4;
            unsigned keep0 = h ? pk[a + 2] : pk[a + 0];
            unsigned keep1 = h ? pk[a + 3] : pk[a + 1];
            unsigned send0 = h ? pk[a + 0] : pk[a + 2];
            unsigned send1 = h ? pk[a + 1] : pk[a + 3];
            unsigned recv0 = (unsigned)__shfl_xor((int)send0, 32);
            unsigned recv1 = (unsigned)__shfl_xor((int)send1, 32);
            union { bf16x8 v8; unsigned u[4]; } pf;
            pf.u[0] = h ? recv0 : keep0;
            pf.u[1] = h ? recv1 : keep1;
            pf.u[2] = h ? keep0 : recv0;
            pf.u[3] = h ? keep1 : recv1;
            const int oct = ko * 2 + h;
            const int d0 = c32, d1 = 32 + c32;
            bf16x8 vf0 = *(const bf16x8*)&Vb[(d0 * 8 + (oct ^ (d0 & 7))) * 8];
            bf16x8 vf1 = *(const bf16x8*)&Vb[(d1 * 8 + (oct ^ (d1 & 7))) * 8];
            acc0 = __builtin_amdgcn_mfma_f32_32x32x16_bf16(vf0, pf.v8, acc0, 0, 0, 0);
            acc1 = __builtin_amdgcn_mfma_f32_32x32x16_bf16(vf1, pf.v8, acc1, 0, 0, 0);
        }
    };

    // 2-phase pipelined K-loop over tile pairs (2 barriers/pair):
    //   prologue stages K(0),K(1); per pair: V flies under QK, next K under PV.
    {
        const int t1 = (1 < nT) ? 1 : 0;
        stageK(0, Ke);
        stageK(t1 * 64, Ko);
    }
    for (int tp = 0; tp < nT; tp += 2) {
        __syncthreads();                  // K(tp),K(tp+1) ready; prior V reads done
        const int to = (tp + 1 < nT) ? tp + 1 : tp;
        stageV(tp * 64, Ve);              // V flies under QK+softmax
        stageV(to * 64, Vo);
        const bool valid = (grp == 0) || (tp + 1 < nT);
        if (valid) qkPhase(grp ? (tp + 1) * 64 : tp * 64, grp ? Ko : Ke);
        __syncthreads();                  // V ready; all K reads done
        if (tp + 2 < nT) {
            const int t3 = (tp + 3 < nT) ? tp + 3 : tp + 2;
            stageK((tp + 2) * 64, Ke);    // next K flies under PV
            stageK(t3 * 64, Ko);
        }
        if (valid) pvPhase(grp ? Vo : Ve);
    }

    // --- merge key-split partials: wave 2->0, 3->1 via LDS ([r][lane]: no
    // bank conflicts), then h-halves of l, then store.
    __syncthreads();
    float* mrg = smem + (wave & 1) * 2176;         // 2 pairs x 2176 f32
    if (wave >= 2) {
#pragma unroll
        for (int r = 0; r < 16; r++) {
            mrg[r * 64 + lane] = acc0[r];
            mrg[(16 + r) * 64 + lane] = acc1[r];
        }
        mrg[2048 + lane] = lacc;
    }
    __syncthreads();
    if (wave >= 2) return;
#pragma unroll
    for (int r = 0; r < 16; r++) {
        acc0[r] += mrg[r * 64 + lane];
        acc1[r] += mrg[(16 + r) * 64 + lane];
    }
    lacc += mrg[2048 + lane];

    const float l = lacc + __shfl_xor(lacc, 32);
    if (!gr) {
        const float inv = 1.0f / l;
        unsigned short* dst = &AO[((size_t)(b * Tc + q)) * Dc + hd * HDc];
#pragma unroll
        for (int i = 0; i < 8; i++) {
            const int r = 2 * i;
            const int d = (r & 3) + 8 * (r >> 2) + 4 * h;
            *(unsigned*)&dst[d]      = pack2bf(acc0[r] * inv, acc0[r + 1] * inv);
            *(unsigned*)&dst[32 + d] = pack2bf(acc1[r] * inv, acc1[r + 1] * inv);
        }
    }
}

// ---------------------------------------------------------------------------
extern "C" void kernel_launch(void* const* d_in, const int* in_sizes, int n_in,
                              void* d_out, int out_size, void* d_ws, size_t ws_size,
                              hipStream_t stream)
{
    const float* x    = (const float*)d_in[0];
    const int*   ids  = (const int*)d_in[1];
    const float* Wqkv = (const float*)d_in[2];
    const float* bqkv = (const float*)d_in[3];
    const float* Wout = (const float*)d_in[4];
    const float* bout = (const float*)d_in[5];
    float* out = (float*)d_out;

    const size_t TEN = (size_t)Bc * Hc * Tc * HDc;   // 4,194,304 elements
    unsigned short* xb    = (unsigned short*)d_ws;            // 4.2M us
    unsigned short* wqkvb = xb + 4194304;                     // 3.1M us
    unsigned short* woutb = wqkvb + 3145728;                  // 1.0M us
    float2* ropeTab       = (float2*)(woutb + 1048576);       // 64K float2
    unsigned short* Qb    = (unsigned short*)(ropeTab + 65536);
    unsigned short* Kb    = Qb + TEN;
    unsigned short* Vtb   = Kb + TEN;
    unsigned short* AOb   = Vtb + TEN;                        // ~51 MB total

    // 0. fp32 -> bf16 conversions + RoPE table (grid-stride x4)
    convert_bf16<<<2048, 256, 0, stream>>>(x, Wqkv, Wout, xb, wqkvb, woutb,
                                           ropeTab);
    // 1. QKV projection (MFMA) + fused RoPE -> bf16 Q/K [b,h,t,d], V^T [b,h,d,t]
    dim3 g1(3072 / 128, 4096 / 128);
    gemm_mfma<1, 4, 4><<<g1, 256, 0, stream>>>(xb, wqkvb, bqkv, nullptr,
                                               Qb, Kb, Vtb, ropeTab,
                                               4096, 3072, 1024);
    // 2. attention (key-split causal, pipelined + (256,4)) -> bf16 AO
    attn_fused<<<1056, 256, 0, stream>>>(Qb, Kb, Vtb, ids, AOb);
    // 3. output projection (MFMA, fp32 out) — 64x64 tiles, 1024 blocks = 4/CU
    dim3 g4(1024 / 64, 4096 / 64);
    gemm_mfma<0, 2, 2><<<g4, 256, 0, stream>>>(AOb, woutb, bout, out,
                                               nullptr, nullptr, nullptr, nullptr,
                                               4096, 1024, 1024);
}

// Round 11
// 183.833 us; speedup vs baseline: 1.2791x; 1.0473x over previous
//
#include <hip/hip_runtime.h>
#include <math.h>

// Problem constants
#define Bc 2
#define Tc 2048
#define Dc 1024
#define Hc 16
#define HDc 64
// M = B*T = 4096, QKV N = 3072, K = 1024

typedef __attribute__((ext_vector_type(8))) short bf16x8;
typedef __attribute__((ext_vector_type(4))) float f32x4;
typedef __attribute__((ext_vector_type(16))) float f32x16;

__device__ __forceinline__ unsigned short f2bf(float f) {
    union { float f; unsigned int u; } v; v.f = f;
    unsigned int r = (v.u + 0x7FFFu + ((v.u >> 16) & 1u)) >> 16;   // RNE
    return (unsigned short)r;
}
// pack two fp32 -> bf16x2 dword (round-nearest, ties up): 3 VALU
__device__ __forceinline__ unsigned pack2bf(float a, float b) {
    unsigned au = __float_as_uint(a) + 0x8000u;
    unsigned bu = __float_as_uint(b) + 0x8000u;
    return __builtin_amdgcn_perm(bu, au, 0x07060302u);
}

// async global->LDS, 16 B per lane. LDS dest is WAVE-UNIFORM base + lane*16.
__device__ __forceinline__ void gload_lds16(const unsigned short* g,
                                            unsigned short* l) {
    __builtin_amdgcn_global_load_lds(
        (const __attribute__((address_space(1))) unsigned int*)g,
        (__attribute__((address_space(3))) unsigned int*)l,
        16, 0, 0);
}

// exp scale: 1/sqrt(64) * log2(e)  (fixed-max softmax: p = exp2(s*CEXP))
#define CEXP 0.1803368801111204f

// ---------------------------------------------------------------------------
// fp32 -> bf16 conversion for x, W_qkv, W_out + RoPE cos/sin table fill.
// Grid-stride (G11): 2048 blocks x 4 iterations of float4.
// ---------------------------------------------------------------------------
__global__ __launch_bounds__(256) void convert_bf16(
    const float* __restrict__ x, const float* __restrict__ wqkv,
    const float* __restrict__ wout,
    unsigned short* __restrict__ xb, unsigned short* __restrict__ wqkvb,
    unsigned short* __restrict__ woutb, float2* __restrict__ ropeTab)
{
    const int gid = blockIdx.x * 256 + threadIdx.x;      // 0..524287
    // RoPE table: 2048 x 32 entries (cos, sin), angle = t * 10000^(-i/32)
    if (gid < Tc * 32) {
        const int t = gid >> 5, i = gid & 31;
        const float freq = exp2f((float)i * -0.4152410118609203f);
        const float ang = (float)t * freq;
        ropeTab[gid] = make_float2(cosf(ang), sinf(ang));
    }
#pragma unroll
    for (int it = 0; it < 4; it++) {
        const int i = (it * 524288 + gid) * 4;           // 8,388,608 floats
        const float* src; unsigned short* dst; int off;
        if (i < 4194304)      { src = x;    dst = xb;    off = i; }
        else if (i < 7340032) { src = wqkv; dst = wqkvb; off = i - 4194304; }
        else                  { src = wout; dst = woutb; off = i - 7340032; }
        float4 v = *(const float4*)&src[off];
        ushort4 o;
        o.x = f2bf(v.x); o.y = f2bf(v.y); o.z = f2bf(v.z); o.w = f2bf(v.w);
        *(ushort4*)&dst[off] = o;
    }
}

// ---------------------------------------------------------------------------
// bf16 MFMA GEMM:  C[M,N] = A[M,K] @ W[N,K]^T + bias[N]
// Block tile (MT*32) x (NT*32), BK=64, 256 thr = 4 waves (2x2),
// per-wave tile (MT*16) x (NT*16) frags of 16x16x32.
//   <1,2,4>: 64x128 QKV + fused RoPE epilogue (Q/K [b,h,t,d]; V^T [b,h,d,t]).
//            R9: 128x128 gave grid 768 = exactly 3 blocks/CU, MfmaUtil 19%,
//            HBM 17% — latency-bound. 64x128 -> 1536 blocks = 6/CU
//            (LDS 24 KB, acc 32 regs); wave owns 32 t-rows of one head.
//   <0,2,2>: 64x64 out-proj (fp32 C + bias) — grid 1024 blocks = 4/CU
// NO XCD remap (R7 lesson): flat%8 band remap raised QKV 50->66us.
// Staging: async global_load_lds width=16 (linear LDS dest), global source
// oct PRE-SWIZZLED so LDS[r][o] = G[r][o ^ (r&7)] -> fragment reads stay
// 2-way-conflict-free.
// ---------------------------------------------------------------------------
template <int MODE, int MT, int NT>
__global__ __launch_bounds__(256) void gemm_mfma(
    const unsigned short* __restrict__ A, const unsigned short* __restrict__ W,
    const float* __restrict__ bias, float* __restrict__ C,
    unsigned short* __restrict__ Qp, unsigned short* __restrict__ Kp,
    unsigned short* __restrict__ Vtp, const float2* __restrict__ ropeTab,
    int M, int N, int K)
{
    __shared__ unsigned short Apk[MT * 32 * 64];
    __shared__ unsigned short Bpk[NT * 32 * 64];

    const int tid = threadIdx.x;
    const int lane = tid & 63;
    const int wave = tid >> 6;
    const int quad = lane >> 4;
    const int c = lane & 15;
    const int wm = wave >> 1;
    const int wn = wave & 1;
    const int m0 = blockIdx.y * (MT * 32);
    const int n0 = blockIdx.x * (NT * 32);

    f32x4 acc[MT][NT];
#pragma unroll
    for (int mt = 0; mt < MT; mt++)
#pragma unroll
        for (int nt = 0; nt < NT; nt++) acc[mt][nt] = (f32x4){0.f, 0.f, 0.f, 0.f};

    // staging: wave-load of 1 KB covers 8 rows x 8 octs. lane -> (row, oct):
    // row_in_chunk = lane>>3, lds oct = lane&7 (fixed by HW linear layout).
    // source oct = (lane&7) ^ (r&7); r&7 == lane>>3 for all 8-aligned chunks.
    const int lrow = lane >> 3;
    const int srcoct = (lane & 7) ^ lrow;

    for (int k0 = 0; k0 < K; k0 += 64) {
        __syncthreads();                       // prior tile's ds_reads done
#pragma unroll
        for (int i = 0; i < MT; i++) {
            const int r = wave * (MT * 8) + i * 8 + lrow;
            gload_lds16(&A[(size_t)(m0 + r) * K + k0 + srcoct * 8],
                        &Apk[(wave * MT * 8 + i * 8) * 64]);
        }
#pragma unroll
        for (int i = 0; i < NT; i++) {
            const int r = wave * (NT * 8) + i * 8 + lrow;
            gload_lds16(&W[(size_t)(n0 + r) * K + k0 + srcoct * 8],
                        &Bpk[(wave * NT * 8 + i * 8) * 64]);
        }
        __syncthreads();                       // drains vmcnt(0): tile ready
#pragma unroll
        for (int ko = 0; ko < 2; ko++) {
            bf16x8 af[MT], bf[NT];
#pragma unroll
            for (int mt = 0; mt < MT; mt++) {
                const int m = wm * (MT * 16) + mt * 16 + c;
                af[mt] = *(const bf16x8*)&Apk[(m * 8 + ((ko * 4 + quad) ^ (m & 7))) * 8];
            }
#pragma unroll
            for (int nt = 0; nt < NT; nt++) {
                const int n = wn * (NT * 16) + nt * 16 + c;
                bf[nt] = *(const bf16x8*)&Bpk[(n * 8 + ((ko * 4 + quad) ^ (n & 7))) * 8];
            }
#pragma unroll
            for (int mt = 0; mt < MT; mt++)
#pragma unroll
                for (int nt = 0; nt < NT; nt++)
                    acc[mt][nt] = __builtin_amdgcn_mfma_f32_16x16x32_bf16(
                        af[mt], bf[nt], acc[mt][nt], 0, 0, 0);
        }
    }

    if (MODE == 0) {
#pragma unroll
        for (int mt = 0; mt < MT; mt++) {
            const int m = m0 + wm * (MT * 16) + mt * 16 + quad * 4;
#pragma unroll
            for (int nt = 0; nt < NT; nt++) {
                const int n = n0 + wn * (NT * 16) + nt * 16 + c;
                const float bv = bias[n];
#pragma unroll
                for (int reg = 0; reg < 4; reg++)
                    C[(size_t)(m + reg) * N + n] = acc[mt][nt][reg] + bv;
            }
        }
    } else {
        // MODE 1 requires NT==4 (wave covers one full 64-wide head: wn*64).
        const int n_wave = n0 + wn * 64;          // 64-aligned -> one head/wave
        const int which = n_wave >> 10;           // 0=q,1=k,2=v (block-uniform)
        const int h = (n_wave >> 6) & 15;
        const int b = m0 >> 11;
        const int t_base = (m0 & 2047) + wm * (MT * 16);   // wave's MT*16 t-rows

        __syncthreads();   // all MFMA LDS reads done; reuse Apk/Bpk as staging
        // per-wave staging region: MT*16 rows x 64 cols = MT*1024 ushorts.
        // waves {0,1} in Apk (MT*2048 us), {2,3} in Bpk.
        unsigned short* stg = ((wave < 2) ? Apk : Bpk) + (wave & 1) * (MT * 1024);

        if (which < 2) {
            // ---- Q/K with fused RoPE: rotate -> LDS tile -> coalesced store
            unsigned short* dst = (which == 0) ? Qp : Kp;
#pragma unroll
            for (int mt = 0; mt < MT; mt++) {
#pragma unroll
                for (int nt = 0; nt < 2; nt++) {
                    const int i1 = nt * 16 + c;            // rotary index 0..31
                    const float bv1 = bias[n_wave + i1];
                    const float bv2 = bias[n_wave + 32 + i1];
#pragma unroll
                    for (int reg = 0; reg < 4; reg++) {
                        const int row = mt * 16 + quad * 4 + reg;   // 0..MT*16-1
                        const float2 cs = ropeTab[(t_base + row) * 32 + i1];
                        const float x1 = acc[mt][nt][reg] + bv1;
                        const float x2 = acc[mt][nt + 2][reg] + bv2;
                        const int col2 = 32 + i1;
                        stg[(row * 8 + ((i1 >> 3) ^ (row & 7))) * 8 + (i1 & 7)] =
                            f2bf(x1 * cs.x - x2 * cs.y);
                        stg[(row * 8 + ((col2 >> 3) ^ (row & 7))) * 8 + (col2 & 7)] =
                            f2bf(x1 * cs.y + x2 * cs.x);
                    }
                }
            }
            // tile [t_base..t_base+MT*16-1][0..63] is contiguous in Q/K
            const size_t obase = ((size_t)(b * Hc + h) * Tc + t_base) * HDc;
            const int oct = lane & 7;
#pragma unroll
            for (int k = 0; k < MT * 2; k++) {
                const int f = lane * 8 + k * 512;       // flat ushort offset
                const int row = f >> 6;
                bf16x8 vv = *(const bf16x8*)&stg[(row * 8 + (oct ^ (row & 7))) * 8];
                *(bf16x8*)&dst[obase + f] = vv;         // 64 lanes x 16 B = 1 KB
            }
        } else {
            // ---- V: stage transposed tile [d][t] (t-span = MT*16 = VO octs)
            constexpr int VO = MT * 2;                  // octs per d-row
#pragma unroll
            for (int mt = 0; mt < MT; mt++) {
#pragma unroll
                for (int nt = 0; nt < 4; nt++) {
                    const int d = nt * 16 + c;
                    const float bv = bias[n_wave + d];
#pragma unroll
                    for (int reg = 0; reg < 4; reg++) {
                        const int r = mt * 16 + quad * 4 + reg;   // t within tile
                        stg[(d * VO + ((r >> 3) ^ (d & (VO - 1)))) * 8 + (r & 7)] =
                            f2bf(acc[mt][nt][reg] + bv);
                    }
                }
            }
            const size_t vbase = (size_t)(b * Hc + h) * HDc * Tc;
            const int oct = lane & (VO - 1);            // t-chunk
#pragma unroll
            for (int k = 0; k < VO; k++) {
                const int d = (lane / VO) + k * (64 / VO);
                bf16x8 vv = *(const bf16x8*)&stg[(d * VO + (oct ^ (d & (VO - 1)))) * 8];
                // VO lanes cover one d-row segment (MT*16 t = VO*16 B)
                *(bf16x8*)&Vtp[vbase + (size_t)d * Tc + t_base + oct * 8] = vv;
            }
        }
    }
}

// ---------------------------------------------------------------------------
// Fused attention — VERBATIM the R9-measured 50.4us version (tree32 qkPhase).
// R10's seq-softmax variant went in alongside the QKV tile change and the
// bench core-dumped; this round bisects: attn reverted to the proven binary,
// QKV <1,2,4> kept. Grid = 1056 blocks:
//   blk 0..31    : global-query rows (full-T, one block per bh).
//   blk 32..1055 : causal, 2-way KEY-SPLIT (fixed-max softmax => O,l partials
//     are linear and just add); forced (256,4) occupancy x 2-phase pipeline:
//       barrier -> stage V(pair) -> QK^T+softmax (V in flight)
//       barrier -> stage K(next pair) -> PV (K in flight)
// ---------------------------------------------------------------------------
__global__ __launch_bounds__(256, 4) void attn_fused(
    const unsigned short* __restrict__ Q, const unsigned short* __restrict__ K,
    const unsigned short* __restrict__ Vt, const int* __restrict__ ids,
    unsigned short* __restrict__ AO)
{
    __shared__ __align__(16) float smem[8448];   // 33792 B, overlaid per path

    const int tid = threadIdx.x;
    const int lane = tid & 63;
    const int wave = tid >> 6;
    const int c32 = lane & 31;
    const int h = lane >> 5;
    const int blk = blockIdx.x;

    if (blk < 32) {
        // ================= global-query rows =================
        int* s_list = (int*)smem;                 // 64
        int* s_cnt = (int*)smem + 64;
        float* s_accm = smem + 128;               // [4][64][32]
        float* s_lm = s_accm + 8192;              // [4][32]

        const int bh = blk;
        const int b = bh >> 4;
        const int hd = bh & 15;
        const size_t qkbase = (size_t)bh * Tc * HDc;

        if (tid == 0) *s_cnt = 0;
        __syncthreads();
        for (int i = tid; i < Tc; i += 256) {
            int id = ids[b * Tc + i];
            if ((unsigned)(id - 2) <= 5u) {
                int p = atomicAdd(s_cnt, 1);
                if (p < 64) s_list[p] = i;
            }
        }
        __syncthreads();
        const int cnt = min(*s_cnt, 64);

        for (int pass = 0; pass * 32 < cnt; pass++) {
            const int slot = pass * 32 + c32;
            const int row = (slot < cnt) ? s_list[slot] : s_list[0];

            bf16x8 qf[4];
#pragma unroll
            for (int ko = 0; ko < 4; ko++)
                qf[ko] = *(const bf16x8*)&Q[qkbase + (size_t)row * HDc + ko * 16 + h * 8];

            f32x16 acc0 = {}, acc1 = {};
            float lacc = 0.0f;

            for (int it = wave; it < Tc / 64; it += 4) {
                const int t0 = it * 64;
                f32x16 s0 = {}, s1 = {};
#pragma unroll
                for (int ko = 0; ko < 4; ko++) {
                    const int koff = ko * 16 + h * 8;
                    bf16x8 kf0 = *(const bf16x8*)&K[qkbase + (size_t)(t0 + c32) * HDc + koff];
                    bf16x8 kf1 = *(const bf16x8*)&K[qkbase + (size_t)(t0 + 32 + c32) * HDc + koff];
                    s0 = __builtin_amdgcn_mfma_f32_32x32x16_bf16(kf0, qf[ko], s0, 0, 0, 0);
                    s1 = __builtin_amdgcn_mfma_f32_32x32x16_bf16(kf1, qf[ko], s1, 0, 0, 0);
                }
                float v[32];
#pragma unroll
                for (int r = 0; r < 16; r++) { v[r] = s0[r]; v[16 + r] = s1[r]; }
#pragma unroll
                for (int i = 0; i < 32; i++) v[i] = exp2f(v[i] * CEXP);
                unsigned pk[16];
#pragma unroll
                for (int i = 0; i < 16; i++) pk[i] = pack2bf(v[2 * i], v[2 * i + 1]);
#pragma unroll
                for (int st = 1; st < 32; st <<= 1)
#pragma unroll
                    for (int i = 0; i < 32; i += 2 * st) v[i] += v[i + st];
                lacc += v[0];
#pragma unroll
                for (int ko = 0; ko < 4; ko++) {
                    const int a = (ko >> 1) * 8 + (ko & 1) * 4;
                    unsigned keep0 = h ? pk[a + 2] : pk[a + 0];
                    unsigned keep1 = h ? pk[a + 3] : pk[a + 1];
                    unsigned send0 = h ? pk[a + 0] : pk[a + 2];
                    unsigned send1 = h ? pk[a + 1] : pk[a + 3];
                    unsigned recv0 = (unsigned)__shfl_xor((int)send0, 32);
                    unsigned recv1 = (unsigned)__shfl_xor((int)send1, 32);
                    union { bf16x8 v8; unsigned u[4]; } pf;
                    pf.u[0] = h ? recv0 : keep0;
                    pf.u[1] = h ? recv1 : keep1;
                    pf.u[2] = h ? keep0 : recv0;
                    pf.u[3] = h ? keep1 : recv1;
                    const int oct = ko * 2 + h;
                    bf16x8 vf0 = *(const bf16x8*)&Vt[qkbase + (size_t)c32 * Tc + t0 + oct * 8];
                    bf16x8 vf1 = *(const bf16x8*)&Vt[qkbase + (size_t)(32 + c32) * Tc + t0 + oct * 8];
                    acc0 = __builtin_amdgcn_mfma_f32_32x32x16_bf16(vf0, pf.v8, acc0, 0, 0, 0);
                    acc1 = __builtin_amdgcn_mfma_f32_32x32x16_bf16(vf1, pf.v8, acc1, 0, 0, 0);
                }
            }

            const float lfull = lacc + __shfl_xor(lacc, 32);
            if (h == 0) s_lm[wave * 32 + c32] = lfull;
#pragma unroll
            for (int r = 0; r < 16; r++) {
                const int d = (r & 3) + 8 * (r >> 2) + 4 * h;
                s_accm[(wave * 64 + d) * 32 + c32] = acc0[r];
                s_accm[(wave * 64 + 32 + d) * 32 + c32] = acc1[r];
            }
            __syncthreads();
            for (int i = tid; i < 2048; i += 256) {
                const int sl = i >> 6, d = i & 63;
                if (pass * 32 + sl < cnt) {
                    const float o = s_accm[(0 * 64 + d) * 32 + sl] + s_accm[(1 * 64 + d) * 32 + sl] +
                                    s_accm[(2 * 64 + d) * 32 + sl] + s_accm[(3 * 64 + d) * 32 + sl];
                    const float lt = s_lm[sl] + s_lm[32 + sl] + s_lm[64 + sl] + s_lm[96 + sl];
                    const int qrow = s_list[pass * 32 + sl];
                    AO[((size_t)(b * Tc + qrow)) * Dc + hd * HDc + d] = f2bf(o / lt);
                }
            }
            __syncthreads();
        }
        return;
    }

    // ====== causal path: key-split + (256,4) + 2-phase pipelined staging =====
    unsigned short* KV = (unsigned short*)smem;
    unsigned short* Ke = KV;                       // even-tile K (8 KB)
    unsigned short* Ko = KV + 4096;                // odd-tile  K
    unsigned short* Ve = KV + 8192;                // even-tile V^T
    unsigned short* Vo = KV + 12288;               // odd-tile  V^T

    const int idx = blk - 32;                      // 0..1023
    const int bh = (idx & 7) + 8 * ((idx >> 3) & 3);   // 4 bh per XCD
    const int b = bh >> 4;
    const int hd = bh & 15;
    // weight index -> j so stride-8 samples {w, w+8, w+16, w+24} (one CU's 4
    // resident blocks) give j = {u, 31-u, 8+u, 23-u}: nTiles sum == 66 const.
    const int w = idx >> 5;                        // 0..31
    const int u = w & 7, tq = w >> 3;
    const int j = (tq == 0) ? u : (tq == 1) ? 31 - u : (tq == 2) ? 8 + u : 23 - u;
    const int qb0 = j * 64;
    const int nT = j + 1;                          // 64-key tiles in [0, qb0+64)
    const int grp = wave >> 1;                     // 0: even tiles, 1: odd
    const int wq0 = qb0 + (wave & 1) * 32;         // wave's 32 q rows
    const size_t qkbase = (size_t)bh * Tc * HDc;
    const int q = wq0 + c32;

    // Q B-fragments (whole kernel): B[k=hd=ko*16+h*8+j][n=q=c32]
    bf16x8 qf[4];
#pragma unroll
    for (int ko = 0; ko < 4; ko++)
        qf[ko] = *(const bf16x8*)&Q[qkbase + (size_t)q * HDc + ko * 16 + h * 8];

    const int myid = ids[b * Tc + q];
    const bool gr = ((unsigned)(myid - 2) <= 5u);  // global row: store suppressed

    f32x16 acc0 = {}, acc1 = {};
    float lacc = 0.0f;

    // staging constants (global_load_lds: linear LDS, pre-swizzled source)
    const int lrow = lane >> 3;                    // 0..7
    const int srcoct = (lane & 7) ^ lrow;          // source oct for this lane
    const int jb = wave * 2;                       // wave's 1-KB chunk base

    auto stageK = [&](int t0, unsigned short* buf) {
#pragma unroll
        for (int i = 0; i < 2; i++) {
            const int jj = jb + i;                 // 0..7 (8 x 1 KB = 8 KB)
            const int row = jj * 8 + lrow;         // key row 0..63
            gload_lds16(&K[qkbase + (size_t)(t0 + row) * HDc + srcoct * 8],
                        &buf[jj * 512]);
        }
    };
    auto stageV = [&](int t0, unsigned short* buf) {
#pragma unroll
        for (int i = 0; i < 2; i++) {
            const int jj = jb + i;
            const int d = jj * 8 + lrow;           // d row 0..63
            gload_lds16(&Vt[qkbase + (size_t)d * Tc + t0 + srcoct * 8],
                        &buf[jj * 512]);
        }
    };

    unsigned pk[16];

    auto qkPhase = [&](int t0, const unsigned short* Kb) {
        // --- scores S^T[key][q]: 2 key-tiles of 32, contraction 64 = 4 MFMAs
        f32x16 s0 = {}, s1 = {};
#pragma unroll
        for (int ko = 0; ko < 4; ko++) {
            const int oct = ko * 2 + h;
            const int k0i = c32;
            const int k1i = 32 + c32;
            bf16x8 kf0 = *(const bf16x8*)&Kb[(k0i * 8 + (oct ^ (k0i & 7))) * 8];
            bf16x8 kf1 = *(const bf16x8*)&Kb[(k1i * 8 + (oct ^ (k1i & 7))) * 8];
            s0 = __builtin_amdgcn_mfma_f32_32x32x16_bf16(kf0, qf[ko], s0, 0, 0, 0);
            s1 = __builtin_amdgcn_mfma_f32_32x32x16_bf16(kf1, qf[ko], s1, 0, 0, 0);
        }

        // --- fixed-max softmax: p = exp2(s*CEXP), no chains, no cross-lane
        float v[32];
#pragma unroll
        for (int r = 0; r < 16; r++) { v[r] = s0[r]; v[16 + r] = s1[r]; }
#pragma unroll
        for (int i = 0; i < 32; i++) v[i] = exp2f(v[i] * CEXP);

        const bool needMask = (t0 + 63 > wq0);     // wave-uniform (diag tile)
        if (needMask) {
            const int thr = wq0 + c32 - t0 - 4 * h;
#pragma unroll
            for (int kt = 0; kt < 2; kt++)
#pragma unroll
                for (int r = 0; r < 16; r++) {
                    const int ckr = kt * 32 + (r & 3) + 8 * (r >> 2);
                    v[kt * 16 + r] = (ckr <= thr) ? v[kt * 16 + r] : 0.0f;
                }
        }

#pragma unroll
        for (int i = 0; i < 16; i++) pk[i] = pack2bf(v[2 * i], v[2 * i + 1]);

        // l accumulation: depth-5 pairwise tree, no cross-lane op
#pragma unroll
        for (int st = 1; st < 32; st <<= 1)
#pragma unroll
            for (int i = 0; i < 32; i += 2 * st) v[i] += v[i + st];
        lacc += v[0];
    };

    auto pvPhase = [&](const unsigned short* Vb) {
        // --- PV: O^T += V^T x P^T
#pragma unroll
        for (int ko = 0; ko < 4; ko++) {
            const int a = (ko >> 1) * 8 + (ko & 1) * 4;
            unsigned keep0 = h ? pk[a + 2] : pk[a + 0];
            unsigned keep1 = h ? pk[a + 3] : pk[a + 1];
            unsigned send0 = h ? pk[a + 0] : pk[a + 2];
            unsigned send1 = h ? pk[a + 1] : pk[a + 3];
            unsigned recv0 = (unsigned)__shfl_xor((int)send0, 32);
            unsigned recv1 = (unsigned)__shfl_xor((int)send1, 32);
            union { bf16x8 v8; unsigned u[4]; } pf;
            pf.u[0] = h ? recv0 : keep0;
            pf.u[1] = h ? recv1 : keep1;
            pf.u[2] = h ? keep0 : recv0;
            pf.u[3] = h ? keep1 : recv1;
            const int oct = ko * 2 + h;
            const int d0 = c32, d1 = 32 + c32;
            bf16x8 vf0 = *(const bf16x8*)&Vb[(d0 * 8 + (oct ^ (d0 & 7))) * 8];
            bf16x8 vf1 = *(const bf16x8*)&Vb[(d1 * 8 + (oct ^ (d1 & 7))) * 8];
            acc0 = __builtin_amdgcn_mfma_f32_32x32x16_bf16(vf0, pf.v8, acc0, 0, 0, 0);
            acc1 = __builtin_amdgcn_mfma_f32_32x32x16_bf16(vf1, pf.v8, acc1, 0, 0, 0);
        }
    };

    // 2-phase pipelined K-loop over tile pairs (2 barriers/pair):
    //   prologue stages K(0),K(1); per pair: V flies under QK, next K under PV.
    {
        const int t1 = (1 < nT) ? 1 : 0;
        stageK(0, Ke);
        stageK(t1 * 64, Ko);
    }
    for (int tp = 0; tp < nT; tp += 2) {
        __syncthreads();                  // K(tp),K(tp+1) ready; prior V reads done
        const int to = (tp + 1 < nT) ? tp + 1 : tp;
        stageV(tp * 64, Ve);              // V flies under QK+softmax
        stageV(to * 64, Vo);
        const bool valid = (grp == 0) || (tp + 1 < nT);
        if (valid) qkPhase(grp ? (tp + 1) * 64 : tp * 64, grp ? Ko : Ke);
        __syncthreads();                  // V ready; all K reads done
        if (tp + 2 < nT) {
            const int t3 = (tp + 3 < nT) ? tp + 3 : tp + 2;
            stageK((tp + 2) * 64, Ke);    // next K flies under PV
            stageK(t3 * 64, Ko);
        }
        if (valid) pvPhase(grp ? Vo : Ve);
    }

    // --- merge key-split partials: wave 2->0, 3->1 via LDS ([r][lane]: no
    // bank conflicts), then h-halves of l, then store.
    __syncthreads();
    float* mrg = smem + (wave & 1) * 2176;         // 2 pairs x 2176 f32
    if (wave >= 2) {
#pragma unroll
        for (int r = 0; r < 16; r++) {
            mrg[r * 64 + lane] = acc0[r];
            mrg[(16 + r) * 64 + lane] = acc1[r];
        }
        mrg[2048 + lane] = lacc;
    }
    __syncthreads();
    if (wave >= 2) return;
#pragma unroll
    for (int r = 0; r < 16; r++) {
        acc0[r] += mrg[r * 64 + lane];
        acc1[r] += mrg[(16 + r) * 64 + lane];
    }
    lacc += mrg[2048 + lane];

    const float l = lacc + __shfl_xor(lacc, 32);
    if (!gr) {
        const float inv = 1.0f / l;
        unsigned short* dst = &AO[((size_t)(b * Tc + q)) * Dc + hd * HDc];
#pragma unroll
        for (int i = 0; i < 8; i++) {
            const int r = 2 * i;
            const int d = (r & 3) + 8 * (r >> 2) + 4 * h;
            *(unsigned*)&dst[d]      = pack2bf(acc0[r] * inv, acc0[r + 1] * inv);
            *(unsigned*)&dst[32 + d] = pack2bf(acc1[r] * inv, acc1[r + 1] * inv);
        }
    }
}

// ---------------------------------------------------------------------------
extern "C" void kernel_launch(void* const* d_in, const int* in_sizes, int n_in,
                              void* d_out, int out_size, void* d_ws, size_t ws_size,
                              hipStream_t stream)
{
    const float* x    = (const float*)d_in[0];
    const int*   ids  = (const int*)d_in[1];
    const float* Wqkv = (const float*)d_in[2];
    const float* bqkv = (const float*)d_in[3];
    const float* Wout = (const float*)d_in[4];
    const float* bout = (const float*)d_in[5];
    float* out = (float*)d_out;

    const size_t TEN = (size_t)Bc * Hc * Tc * HDc;   // 4,194,304 elements
    unsigned short* xb    = (unsigned short*)d_ws;            // 4.2M us
    unsigned short* wqkvb = xb + 4194304;                     // 3.1M us
    unsigned short* woutb = wqkvb + 3145728;                  // 1.0M us
    float2* ropeTab       = (float2*)(woutb + 1048576);       // 64K float2
    unsigned short* Qb    = (unsigned short*)(ropeTab + 65536);
    unsigned short* Kb    = Qb + TEN;
    unsigned short* Vtb   = Kb + TEN;
    unsigned short* AOb   = Vtb + TEN;                        // ~51 MB total

    // 0. fp32 -> bf16 conversions + RoPE table (grid-stride x4)
    convert_bf16<<<2048, 256, 0, stream>>>(x, Wqkv, Wout, xb, wqkvb, woutb,
                                           ropeTab);
    // 1. QKV projection (MFMA) + fused RoPE -> bf16 Q/K [b,h,t,d], V^T [b,h,d,t]
    //    64x128 tiles -> 1536 blocks = 6/CU (was 768 = 3/CU at 128x128)
    dim3 g1(3072 / 128, 4096 / 64);
    gemm_mfma<1, 2, 4><<<g1, 256, 0, stream>>>(xb, wqkvb, bqkv, nullptr,
                                               Qb, Kb, Vtb, ropeTab,
                                               4096, 3072, 1024);
    // 2. attention (key-split causal, pipelined + (256,4)) -> bf16 AO
    attn_fused<<<1056, 256, 0, stream>>>(Qb, Kb, Vtb, ids, AOb);
    // 3. output projection (MFMA, fp32 out) — 64x64 tiles, 1024 blocks = 4/CU
    dim3 g4(1024 / 64, 4096 / 64);
    gemm_mfma<0, 2, 2><<<g4, 256, 0, stream>>>(AOb, woutb, bout, out,
                                               nullptr, nullptr, nullptr, nullptr,
                                               4096, 1024, 1024);
}